// Round 1
// baseline (4616.903 us; speedup 1.0000x reference)
//
#include <hip/hip_runtime.h>

#define N_NODES 50176
#define PER 392
#define E_BI (N_NODES * 4)
#define E_KNN (N_NODES * 16)

__device__ __forceinline__ float sigmoidf_(float x) { return 1.f / (1.f + __expf(-x)); }

// ---------------- generic fp32 tiled GEMM ----------------
// C[M,N] = (accum? C + : ) act( A[M,K] @ B[K,N] + bias )
// BM=BN=64, BK=32, 256 threads, 4x4 microtile. All M,N multiples of 64; K multiple of 32.
__global__ __launch_bounds__(256) void gemm_kernel(
    const float* __restrict__ A, int lda,
    const float* __restrict__ B, int ldb,
    const float* __restrict__ bias,
    float* __restrict__ C, int ldc,
    int K, int act, int accum)
{
    __shared__ float As[32][68];   // [k][m], padded stride 68 (68*4B=272B, 16B-aligned)
    __shared__ float Bs[32][68];   // [k][n]
    const int tid = threadIdx.x;
    const int bm = blockIdx.x * 64;
    const int bn = blockIdx.y * 64;
    const int tm = (tid & 15) * 4;
    const int tn = (tid >> 4) * 4;
    float acc[4][4] = {};

    for (int k0 = 0; k0 < K; k0 += 32) {
#pragma unroll
        for (int p = 0; p < 2; p++) {
            int lin = p * 256 + tid;
            int ar = lin >> 3;             // 0..63
            int ac = (lin & 7) << 2;       // 0..28
            float4 av = *(const float4*)(A + (size_t)(bm + ar) * lda + (k0 + ac));
            As[ac + 0][ar] = av.x;
            As[ac + 1][ar] = av.y;
            As[ac + 2][ar] = av.z;
            As[ac + 3][ar] = av.w;
            int br = lin >> 4;             // 0..31
            int bc = (lin & 15) << 2;      // 0..60
            *(float4*)&Bs[br][bc] = *(const float4*)(B + (size_t)(k0 + br) * ldb + (bn + bc));
        }
        __syncthreads();
#pragma unroll
        for (int k = 0; k < 32; k++) {
            float4 a4 = *(const float4*)&As[k][tm];
            float4 b4 = *(const float4*)&Bs[k][tn];
            float av[4] = {a4.x, a4.y, a4.z, a4.w};
            float bv[4] = {b4.x, b4.y, b4.z, b4.w};
#pragma unroll
            for (int i = 0; i < 4; i++)
#pragma unroll
                for (int j = 0; j < 4; j++)
                    acc[i][j] += av[i] * bv[j];
        }
        __syncthreads();
    }

#pragma unroll
    for (int i = 0; i < 4; i++) {
        size_t row = (size_t)(bm + tm + i);
#pragma unroll
        for (int j = 0; j < 4; j++) {
            int col = bn + tn + j;
            float val = acc[i][j];
            if (bias) val += bias[col];
            if (act == 1) val = fmaxf(val, 0.f);
            float* cp = C + row * ldc + col;
            if (accum) *cp += val;
            else       *cp = val;
        }
    }
}

static inline void gemm(hipStream_t st, const float* A, int lda, const float* B, int ldb,
                        const float* bias, float* C, int ldc, int M, int N, int K,
                        int act, int accum)
{
    dim3 grid(M / 64, N / 64);
    gemm_kernel<<<grid, 256, 0, st>>>(A, lda, B, ldb, bias, C, ldc, K, act, accum);
}

// ---------------- pad / copy feat -> h (zero-extend to 128 cols) ----------------
__global__ void pad_kernel(const float* __restrict__ f, float* __restrict__ h, int Fin)
{
    int idx = blockIdx.x * blockDim.x + threadIdx.x;   // over N*128 exactly
    int c = idx & 127;
    int v = idx >> 7;
    h[idx] = (c < Fin) ? f[(size_t)v * Fin + c] : 0.f;
}

// ---------------- scatter: a[dst[e]] += t[src[e]] for edges with etype==et ----------------
__global__ void scatter_kernel(const float* __restrict__ t,
                               const int* __restrict__ src, const int* __restrict__ dst,
                               const int* __restrict__ etype, int E, int et,
                               float* __restrict__ a)
{
    int gid = blockIdx.x * blockDim.x + threadIdx.x;   // E*128 threads, 128 per edge
    int e = gid >> 7;
    if (e >= E) return;
    if (etype[e] != et) return;
    int c = gid & 127;
    atomicAdd(a + (size_t)dst[e] * 128 + c, t[(size_t)src[e] * 128 + c]);
}

// ---------------- GRU gate: h = (1-z)*tanh(in + r*hn) + z*h ----------------
__global__ void gru_gate_kernel(const float* __restrict__ rpre, const float* __restrict__ zpre,
                                const float* __restrict__ inb, const float* __restrict__ hnb,
                                float* __restrict__ h)
{
    int idx = blockIdx.x * blockDim.x + threadIdx.x;   // over N*128 exactly
    float r = sigmoidf_(rpre[idx]);
    float z = sigmoidf_(zpre[idx]);
    float n = tanhf(inb[idx] + r * hnb[idx]);
    h[idx] = (1.f - z) * n + z * h[idx];
}

// ---------------- readout elementwise: o = sigmoid(u) * v ----------------
__global__ void sigmul_kernel(const float* __restrict__ u, const float* __restrict__ v,
                              float* __restrict__ o)
{
    int idx = blockIdx.x * blockDim.x + threadIdx.x;
    o[idx] = sigmoidf_(u[idx]) * v[idx];
}

// ---------------- segment pooling over even (ligand) segments ----------------
__global__ void pool_kernel(const float* __restrict__ r2, float* __restrict__ pooled)
{
    int s = blockIdx.x;          // 0..63 -> segment 2s
    int c = threadIdx.x;         // 0..127
    const float* base = r2 + (size_t)(2 * s) * PER * 128;
    float acc = 0.f;
    for (int i = 0; i < PER; i++) acc += base[(size_t)i * 128 + c];
    pooled[s * 128 + c] = acc;
}

// ---------------- final dot: out[row] = x2[row,:] . wo + bo ----------------
__global__ void out_kernel(const float* __restrict__ x2, const float* __restrict__ wo,
                           const float* __restrict__ bo, float* __restrict__ out)
{
    int row = blockIdx.x;
    int t = threadIdx.x;         // 64 threads = one wave
    float s = x2[row * 128 + t] * wo[t] + x2[row * 128 + 64 + t] * wo[64 + t];
#pragma unroll
    for (int off = 32; off; off >>= 1) s += __shfl_down(s, off);
    if (t == 0) out[row] = s + bo[0];
}

struct GGParams {
    const float *W, *b, *wih, *whh, *bih, *bhh, *iw, *ib, *jw, *jb;
};

// One gated-graph-conv stage (2 message-passing steps + GRU + readout).
static void run_stage(hipStream_t st, const float* featS, int Fin,
                      const int* src, const int* dst, const int* et, int E, int n_et,
                      const GGParams& p,
                      float* h, float* a, float* t, float* zb, float* nb, float* ib2,
                      float* rout)
{
    const int N = N_NODES;
    const size_t n128 = (size_t)N * 128;
    pad_kernel<<<(N * 128) / 256, 256, 0, st>>>(featS, h, Fin);
    for (int step = 0; step < 2; step++) {
        hipMemsetAsync(a, 0, n128 * sizeof(float), st);
        for (int i = 0; i < n_et; i++) {
            // t = h @ W[i] + b[i]  (per-edge bias folded into node transform)
            gemm(st, h, 128, p.W + (size_t)i * 128 * 128, 128, p.b + (size_t)i * 128,
                 t, 128, N, 128, 128, 0, 0);
            scatter_kernel<<<(E * 128) / 256, 256, 0, st>>>(t, src, dst, et, E, i, a);
        }
        // r pre-activation (t buffer reused)
        gemm(st, a, 128, p.wih,       384, p.bih,       t,   128, N, 128, 128, 0, 0);
        gemm(st, h, 128, p.whh,       384, p.bhh,       t,   128, N, 128, 128, 0, 1);
        // z pre-activation
        gemm(st, a, 128, p.wih + 128, 384, p.bih + 128, zb,  128, N, 128, 128, 0, 0);
        gemm(st, h, 128, p.whh + 128, 384, p.bhh + 128, zb,  128, N, 128, 128, 0, 1);
        // in = a@wih_n + bih_n ; hn = h@whh_n + bhh_n (kept separate: n = tanh(in + r*hn))
        gemm(st, a, 128, p.wih + 256, 384, p.bih + 256, ib2, 128, N, 128, 128, 0, 0);
        gemm(st, h, 128, p.whh + 256, 384, p.bhh + 256, nb,  128, N, 128, 128, 0, 0);
        gru_gate_kernel<<<(N * 128) / 256, 256, 0, st>>>(t, zb, ib2, nb, h);
    }
    // readout: rout = sigmoid(h@iw_top + featS@iw_bot + ib) * (h@jw + jb)
    gemm(st, h,     128, p.iw,                     128, p.ib,   a, 128, N, 128, 128, 0, 0);
    gemm(st, featS, Fin, p.iw + (size_t)128 * 128, 128, nullptr, a, 128, N, 128, Fin, 0, 1);
    gemm(st, h,     128, p.jw,                     128, p.jb,   t, 128, N, 128, 128, 0, 0);
    sigmul_kernel<<<(N * 128) / 256, 256, 0, st>>>(a, t, rout);
}

extern "C" void kernel_launch(void* const* d_in, const int* in_sizes, int n_in,
                              void* d_out, int out_size, void* d_ws, size_t ws_size,
                              hipStream_t stream)
{
    const float* feat    = (const float*)d_in[0];
    const int*   bi_src  = (const int*)d_in[1];
    const int*   bi_dst  = (const int*)d_in[2];
    const int*   bi_et   = (const int*)d_in[3];
    const int*   knn_src = (const int*)d_in[4];
    const int*   knn_dst = (const int*)d_in[5];
    const int*   knn_et  = (const int*)d_in[6];
    // d_in[7] = batch_num_nodes (constant 392 per segment; folded into PER)

    GGParams s1 { (const float*)d_in[8],  (const float*)d_in[9],  (const float*)d_in[10],
                  (const float*)d_in[11], (const float*)d_in[12], (const float*)d_in[13],
                  (const float*)d_in[14], (const float*)d_in[15], (const float*)d_in[16],
                  (const float*)d_in[17] };
    GGParams s2 { (const float*)d_in[18], (const float*)d_in[19], (const float*)d_in[20],
                  (const float*)d_in[21], (const float*)d_in[22], (const float*)d_in[23],
                  (const float*)d_in[24], (const float*)d_in[25], (const float*)d_in[26],
                  (const float*)d_in[27] };
    const float* w0 = (const float*)d_in[28];
    const float* b0 = (const float*)d_in[29];
    const float* w1 = (const float*)d_in[30];
    const float* b1 = (const float*)d_in[31];
    const float* wo = (const float*)d_in[32];
    const float* bo = (const float*)d_in[33];

    float* ws = (float*)d_ws;
    const size_t n128 = (size_t)N_NODES * 128;
    // workspace layout (all fp32): 7 * N*128 node buffers + tiny MLP buffers ≈ 180 MB
    float* h      = ws;
    float* a      = h   + n128;
    float* r1     = a   + n128;
    float* t      = r1  + n128;
    float* zb     = t   + n128;
    float* nb     = zb  + n128;
    float* ib2    = nb  + n128;
    float* pooled = ib2 + n128;          // 64*128
    float* x1     = pooled + 64 * 128;   // 64*256
    float* x2     = x1 + 64 * 256;       // 64*128

    // Stage 1: covalent-bond graph (5 edge types), feat width 64
    run_stage(stream, feat, 64, bi_src, bi_dst, bi_et, E_BI, 5, s1,
              h, a, t, zb, nb, ib2, r1);
    // Stage 2: knn spatial graph (9 edge types), feat = stage-1 readout (width 128)
    run_stage(stream, r1, 128, knn_src, knn_dst, knn_et, E_KNN, 9, s2,
              h, a, t, zb, nb, ib2, zb);   // rout -> zb (free after last GRU)

    // Stage 3: ligand-segment pooling + MLP
    pool_kernel<<<64, 128, 0, stream>>>(zb, pooled);
    gemm(stream, pooled, 128, w0, 256, b0, x1, 256, 64, 256, 128, 1, 0);
    gemm(stream, x1,     256, w1, 128, b1, x2, 128, 64, 128, 256, 1, 0);
    out_kernel<<<64, 64, 0, stream>>>(x2, wo, bo, (float*)d_out);
}

// Round 2
// 2409.726 us; speedup vs baseline: 1.9159x; 1.9159x over previous
//
#include <hip/hip_runtime.h>
#include <hip/hip_bf16.h>

#define N_NODES 50176
#define PER 392
#define E_BI (N_NODES * 4)      // 200704
#define E_KNN (N_NODES * 16)    // 802816
#define SCAN_BLOCKS 196         // 196*256 == 50176

__device__ __forceinline__ float sigmoidf_(float x) { return 1.f / (1.f + __expf(-x)); }

// ---------------- generic fp32 tiled GEMM ----------------
// C[M,N] = (accum? C + : ) act( A[M,K] @ B[K,N] + bias ),  optional bf16 store
__global__ __launch_bounds__(256) void gemm_kernel(
    const float* __restrict__ A, int lda,
    const float* __restrict__ B, int ldb,
    const float* __restrict__ bias,
    float* __restrict__ C, int ldc,
    int K, int act, int accum, int out_bf16)
{
    __shared__ float As[32][68];
    __shared__ float Bs[32][68];
    const int tid = threadIdx.x;
    const int bm = blockIdx.x * 64;
    const int bn = blockIdx.y * 64;
    const int tm = (tid & 15) * 4;
    const int tn = (tid >> 4) * 4;
    float acc[4][4] = {};

    for (int k0 = 0; k0 < K; k0 += 32) {
#pragma unroll
        for (int p = 0; p < 2; p++) {
            int lin = p * 256 + tid;
            int ar = lin >> 3;
            int ac = (lin & 7) << 2;
            float4 av = *(const float4*)(A + (size_t)(bm + ar) * lda + (k0 + ac));
            As[ac + 0][ar] = av.x;
            As[ac + 1][ar] = av.y;
            As[ac + 2][ar] = av.z;
            As[ac + 3][ar] = av.w;
            int br = lin >> 4;
            int bc = (lin & 15) << 2;
            *(float4*)&Bs[br][bc] = *(const float4*)(B + (size_t)(k0 + br) * ldb + (bn + bc));
        }
        __syncthreads();
#pragma unroll
        for (int k = 0; k < 32; k++) {
            float4 a4 = *(const float4*)&As[k][tm];
            float4 b4 = *(const float4*)&Bs[k][tn];
            float av[4] = {a4.x, a4.y, a4.z, a4.w};
            float bv[4] = {b4.x, b4.y, b4.z, b4.w};
#pragma unroll
            for (int i = 0; i < 4; i++)
#pragma unroll
                for (int j = 0; j < 4; j++)
                    acc[i][j] += av[i] * bv[j];
        }
        __syncthreads();
    }

#pragma unroll
    for (int i = 0; i < 4; i++) {
        size_t row = (size_t)(bm + tm + i);
#pragma unroll
        for (int j = 0; j < 4; j++) {
            int col = bn + tn + j;
            float val = acc[i][j];
            if (bias) val += bias[col];
            if (act == 1) val = fmaxf(val, 0.f);
            if (out_bf16) {
                ((__hip_bfloat16*)C)[row * ldc + col] = __float2bfloat16(val);
            } else {
                float* cp = C + row * ldc + col;
                if (accum) *cp += val;
                else       *cp = val;
            }
        }
    }
}

static inline void gemm(hipStream_t st, const float* A, int lda, const float* B, int ldb,
                        const float* bias, float* C, int ldc, int M, int N, int K,
                        int act, int accum, int out_bf16 = 0)
{
    dim3 grid(M / 64, N / 64);
    gemm_kernel<<<grid, 256, 0, st>>>(A, lda, B, ldb, bias, C, ldc, K, act, accum, out_bf16);
}

// ---------------- W[n_et,128,128] -> Bcat[k, i*128+c] ----------------
__global__ void wtrans_kernel(const float* __restrict__ W, float* __restrict__ Bcat, int n_et)
{
    int idx = blockIdx.x * blockDim.x + threadIdx.x;  // n_et*16384 exactly
    int i = idx >> 14;
    int k = (idx >> 7) & 127;
    int c = idx & 127;
    Bcat[(size_t)k * (n_et * 128) + i * 128 + c] = W[idx];
}

// ---------------- CSR build ----------------
__global__ void hist_kernel(const int* __restrict__ dst, int E, int* __restrict__ counts)
{
    int e = blockIdx.x * blockDim.x + threadIdx.x;
    if (e < E) atomicAdd(&counts[dst[e]], 1);
}

__global__ void scan1_kernel(const int* __restrict__ counts, int* __restrict__ local_ex,
                             int* __restrict__ partial)
{
    __shared__ int s[256];
    int t = threadIdx.x;
    int i = blockIdx.x * 256 + t;
    int v = counts[i];
    s[t] = v;
    __syncthreads();
    for (int off = 1; off < 256; off <<= 1) {
        int x = 0;
        if (t >= off) x = s[t - off];
        __syncthreads();
        if (t >= off) s[t] += x;
        __syncthreads();
    }
    local_ex[i] = s[t] - v;                    // exclusive within block
    if (t == 255) partial[blockIdx.x] = s[255];
}

__global__ void scan2_kernel(int* __restrict__ partial, int nb, int* __restrict__ indptr_last, int E)
{
    __shared__ int s[256];
    int t = threadIdx.x;
    int v = (t < nb) ? partial[t] : 0;
    s[t] = v;
    __syncthreads();
    for (int off = 1; off < 256; off <<= 1) {
        int x = 0;
        if (t >= off) x = s[t - off];
        __syncthreads();
        if (t >= off) s[t] += x;
        __syncthreads();
    }
    if (t < nb) partial[t] = s[t] - v;         // exclusive block offsets
    if (t == 0) *indptr_last = E;
}

__global__ void scan3_kernel(int* __restrict__ indptr, const int* __restrict__ partial)
{
    int i = blockIdx.x * 256 + threadIdx.x;
    indptr[i] += partial[blockIdx.x];
}

__global__ void copy_int_kernel(const int* __restrict__ a, int* __restrict__ b)
{
    int i = blockIdx.x * blockDim.x + threadIdx.x;
    b[i] = a[i];
}

__global__ void fill_kernel(const int* __restrict__ src, const int* __restrict__ dst,
                            const int* __restrict__ et, int E,
                            int* __restrict__ cursor, int* __restrict__ packed)
{
    int e = blockIdx.x * blockDim.x + threadIdx.x;
    if (e >= E) return;
    int pos = atomicAdd(&cursor[dst[e]], 1);
    packed[pos] = src[e] | (et[e] << 20);
}

// ---------------- CSR gather: a[v] = sum_{e in in(v)} tcat[src_e, et_e*128 + c] ----------------
__global__ __launch_bounds__(128) void gather_kernel(
    const __hip_bfloat16* __restrict__ tcat, int stride,
    const int* __restrict__ indptr, const int* __restrict__ packed,
    float* __restrict__ a)
{
    int v = blockIdx.x;
    int c = threadIdx.x;      // 0..127
    int beg = indptr[v], end = indptr[v + 1];
    float acc = 0.f;
    for (int j = beg; j < end; j++) {
        int p = packed[j];
        int srcn = p & 0xFFFFF;
        int et = p >> 20;
        acc += __bfloat162float(tcat[(size_t)srcn * stride + et * 128 + c]);
    }
    a[(size_t)v * 128 + c] = acc;
}

// ---------------- pad / copy feat -> h ----------------
__global__ void pad_kernel(const float* __restrict__ f, float* __restrict__ h, int Fin)
{
    int idx = blockIdx.x * blockDim.x + threadIdx.x;
    int c = idx & 127;
    int v = idx >> 7;
    h[idx] = (c < Fin) ? f[(size_t)v * Fin + c] : 0.f;
}

// ---------------- GRU gate ----------------
__global__ void gru_gate_kernel(const float* __restrict__ rpre, const float* __restrict__ zpre,
                                const float* __restrict__ inb, const float* __restrict__ hnb,
                                float* __restrict__ h)
{
    int idx = blockIdx.x * blockDim.x + threadIdx.x;
    float r = sigmoidf_(rpre[idx]);
    float z = sigmoidf_(zpre[idx]);
    float n = tanhf(inb[idx] + r * hnb[idx]);
    h[idx] = (1.f - z) * n + z * h[idx];
}

__global__ void sigmul_kernel(const float* __restrict__ u, const float* __restrict__ v,
                              float* __restrict__ o)
{
    int idx = blockIdx.x * blockDim.x + threadIdx.x;
    o[idx] = sigmoidf_(u[idx]) * v[idx];
}

__global__ void pool_kernel(const float* __restrict__ r2, float* __restrict__ pooled)
{
    int s = blockIdx.x;
    int c = threadIdx.x;
    const float* base = r2 + (size_t)(2 * s) * PER * 128;
    float acc = 0.f;
    for (int i = 0; i < PER; i++) acc += base[(size_t)i * 128 + c];
    pooled[s * 128 + c] = acc;
}

__global__ void out_kernel(const float* __restrict__ x2, const float* __restrict__ wo,
                           const float* __restrict__ bo, float* __restrict__ out)
{
    int row = blockIdx.x;
    int t = threadIdx.x;
    float s = x2[row * 128 + t] * wo[t] + x2[row * 128 + 64 + t] * wo[64 + t];
#pragma unroll
    for (int off = 32; off; off >>= 1) s += __shfl_down(s, off);
    if (t == 0) out[row] = s + bo[0];
}

struct GGParams {
    const float *W, *b, *wih, *whh, *bih, *bhh, *iw, *ib, *jw, *jb;
};

// One gated-graph-conv stage.
static void run_stage(hipStream_t st, const float* featS, int Fin,
                      const int* src, const int* dst, const int* et, int E, int n_et,
                      const GGParams& p,
                      float* h, float* a, float* big, float* bcat,
                      int* indptr, int* cursor, int* partial, int* packed,
                      float* rout)
{
    const int N = N_NODES;
    const size_t n128 = (size_t)N * 128;
    const int stride = n_et * 128;
    __hip_bfloat16* tcat = (__hip_bfloat16*)big;
    float* rpre = big;
    float* zpre = big + n128;
    float* inb  = big + 2 * n128;
    float* hnb  = big + 3 * n128;

    // --- W transpose -> Bcat ---
    wtrans_kernel<<<(n_et * 16384) / 256, 256, 0, st>>>(p.W, bcat, n_et);

    // --- CSR build (by dst) ---
    hipMemsetAsync(cursor, 0, N * sizeof(int), st);                 // counts
    hist_kernel<<<(E + 255) / 256, 256, 0, st>>>(dst, E, cursor);
    scan1_kernel<<<SCAN_BLOCKS, 256, 0, st>>>(cursor, indptr, partial);
    scan2_kernel<<<1, 256, 0, st>>>(partial, SCAN_BLOCKS, indptr + N, E);
    scan3_kernel<<<SCAN_BLOCKS, 256, 0, st>>>(indptr, partial);
    copy_int_kernel<<<SCAN_BLOCKS, 256, 0, st>>>(indptr, cursor);
    fill_kernel<<<(E + 255) / 256, 256, 0, st>>>(src, dst, et, E, cursor, packed);

    pad_kernel<<<(N * 128) / 256, 256, 0, st>>>(featS, h, Fin);
    for (int step = 0; step < 2; step++) {
        // tcat = h @ Bcat + bcat_bias  (bf16 store)
        gemm(st, h, 128, bcat, stride, p.b, (float*)tcat, stride, N, stride, 128, 0, 0, 1);
        gather_kernel<<<N, 128, 0, st>>>(tcat, stride, indptr, packed, a);
        // GRU pre-activations
        gemm(st, a, 128, p.wih,       384, p.bih,       rpre, 128, N, 128, 128, 0, 0);
        gemm(st, h, 128, p.whh,       384, p.bhh,       rpre, 128, N, 128, 128, 0, 1);
        gemm(st, a, 128, p.wih + 128, 384, p.bih + 128, zpre, 128, N, 128, 128, 0, 0);
        gemm(st, h, 128, p.whh + 128, 384, p.bhh + 128, zpre, 128, N, 128, 128, 0, 1);
        gemm(st, a, 128, p.wih + 256, 384, p.bih + 256, inb,  128, N, 128, 128, 0, 0);
        gemm(st, h, 128, p.whh + 256, 384, p.bhh + 256, hnb,  128, N, 128, 128, 0, 0);
        gru_gate_kernel<<<(N * 128) / 256, 256, 0, st>>>(rpre, zpre, inb, hnb, h);
    }
    // readout: rout = sigmoid(h@iw_top + featS@iw_bot + ib) * (h@jw + jb)
    gemm(st, h,     128, p.iw,                     128, p.ib,    rpre, 128, N, 128, 128, 0, 0);
    gemm(st, featS, Fin, p.iw + (size_t)128 * 128, 128, nullptr, rpre, 128, N, 128, Fin, 0, 1);
    gemm(st, h,     128, p.jw,                     128, p.jb,    zpre, 128, N, 128, 128, 0, 0);
    sigmul_kernel<<<(N * 128) / 256, 256, 0, st>>>(rpre, zpre, rout);
}

extern "C" void kernel_launch(void* const* d_in, const int* in_sizes, int n_in,
                              void* d_out, int out_size, void* d_ws, size_t ws_size,
                              hipStream_t stream)
{
    const float* feat    = (const float*)d_in[0];
    const int*   bi_src  = (const int*)d_in[1];
    const int*   bi_dst  = (const int*)d_in[2];
    const int*   bi_et   = (const int*)d_in[3];
    const int*   knn_src = (const int*)d_in[4];
    const int*   knn_dst = (const int*)d_in[5];
    const int*   knn_et  = (const int*)d_in[6];

    GGParams s1 { (const float*)d_in[8],  (const float*)d_in[9],  (const float*)d_in[10],
                  (const float*)d_in[11], (const float*)d_in[12], (const float*)d_in[13],
                  (const float*)d_in[14], (const float*)d_in[15], (const float*)d_in[16],
                  (const float*)d_in[17] };
    GGParams s2 { (const float*)d_in[18], (const float*)d_in[19], (const float*)d_in[20],
                  (const float*)d_in[21], (const float*)d_in[22], (const float*)d_in[23],
                  (const float*)d_in[24], (const float*)d_in[25], (const float*)d_in[26],
                  (const float*)d_in[27] };
    const float* w0 = (const float*)d_in[28];
    const float* b0 = (const float*)d_in[29];
    const float* w1 = (const float*)d_in[30];
    const float* b1 = (const float*)d_in[31];
    const float* wo = (const float*)d_in[32];
    const float* bo = (const float*)d_in[33];

    const int N = N_NODES;
    const size_t n128 = (size_t)N * 128;
    const size_t big_floats = (size_t)9 * 128 * N / 2;   // knn tcat bf16 region (>= 4*n128)

    float* ws  = (float*)d_ws;
    float* h   = ws;
    float* a   = h + n128;
    float* r1  = a + n128;
    float* big = r1 + n128;
    float* bcat = big + big_floats;                      // 9*16384 floats max
    int* indptr  = (int*)(bcat + 9 * 16384);             // padded to 50436 + last
    int* cursor  = indptr + 50440;                       // N (also counts scratch)
    int* partial = cursor + N;                           // 256
    int* packed  = partial + 256;                        // E_KNN
    float* pooled = (float*)(packed + E_KNN + 4);        // keep 16B alignment
    float* x1 = pooled + 64 * 128;
    float* x2 = x1 + 64 * 256;

    // Stage 1: bond graph (5 etypes), feat width 64
    run_stage(stream, feat, 64, bi_src, bi_dst, bi_et, E_BI, 5, s1,
              h, a, big, bcat, indptr, cursor, partial, packed, r1);
    // Stage 2: knn graph (9 etypes), feat = stage-1 readout
    float* rout2 = big + 2 * n128;   // free slot after last GRU step
    run_stage(stream, r1, 128, knn_src, knn_dst, knn_et, E_KNN, 9, s2,
              h, a, big, bcat, indptr, cursor, partial, packed, rout2);

    // Stage 3: ligand pooling + MLP
    pool_kernel<<<64, 128, 0, stream>>>(rout2, pooled);
    gemm(stream, pooled, 128, w0, 256, b0, x1, 256, 64, 256, 128, 1, 0);
    gemm(stream, x1,     256, w1, 128, b1, x2, 128, 64, 128, 256, 1, 0);
    out_kernel<<<64, 64, 0, stream>>>(x2, wo, bo, (float*)d_out);
}

// Round 3
// 1190.860 us; speedup vs baseline: 3.8769x; 2.0235x over previous
//
#include <hip/hip_runtime.h>
#include <hip/hip_bf16.h>

#define N_NODES 50176
#define PER 392
#define E_BI (N_NODES * 4)      // 200704
#define E_KNN (N_NODES * 16)    // 802816
#define SCAN_BLOCKS 196         // 196*256 == 50176

typedef __attribute__((ext_vector_type(8))) short short8;
typedef __attribute__((ext_vector_type(4))) float float4v;

__device__ __forceinline__ float sigmoidf_(float x) { return 1.f / (1.f + __expf(-x)); }

// ================= bf16 MFMA GEMM =================
// C[M,N] = act-free ( A[M,K]_bf16 @ B[K,N]_bf16 + bias + bias2 )
// Bt is B stored transposed: Bt[n][k], leading dim ldb (= K normally).
// Tile 128x128, 256 threads = 4 waves, each wave 64x64 via 4x4 mfma_16x16x32.
// M,N multiples of 128; K multiple of 32.
__global__ __launch_bounds__(256) void mgemm_kernel(
    const __hip_bfloat16* __restrict__ A, int lda,
    const __hip_bfloat16* __restrict__ Bt, int ldb,
    const float* __restrict__ bias, const float* __restrict__ bias2,
    void* __restrict__ C, int ldc, int K,
    int out_bf16, int accum)
{
    __shared__ short As[128 * 32];
    __shared__ short Bs[128 * 32];
    const int tid = threadIdx.x;
    const int bm = blockIdx.x * 128;
    const int bn = blockIdx.y * 128;
    const int wave = tid >> 6, lane = tid & 63;
    const int quad = lane >> 4, lrow = lane & 15;
    const int wr = wave & 1, wc = wave >> 1;

    const short* Ap = (const short*)A;
    const short* Bp = (const short*)Bt;

    float4v acc[4][4] = {};

    for (int k0 = 0; k0 < K; k0 += 32) {
        __syncthreads();
#pragma unroll
        for (int p = 0; p < 2; p++) {
            int lin = p * 256 + tid;      // 0..511
            int r = lin >> 2;             // 0..127
            int kc = (lin & 3) * 8;       // 0,8,16,24
            *(short8*)&As[r * 32 + kc] = *(const short8*)(Ap + (size_t)(bm + r) * lda + k0 + kc);
            *(short8*)&Bs[r * 32 + kc] = *(const short8*)(Bp + (size_t)(bn + r) * ldb + k0 + kc);
        }
        __syncthreads();
        short8 af[4], bfr[4];
#pragma unroll
        for (int i = 0; i < 4; i++)
            af[i] = *(const short8*)&As[(wr * 64 + i * 16 + lrow) * 32 + quad * 8];
#pragma unroll
        for (int j = 0; j < 4; j++)
            bfr[j] = *(const short8*)&Bs[(wc * 64 + j * 16 + lrow) * 32 + quad * 8];
#pragma unroll
        for (int i = 0; i < 4; i++)
#pragma unroll
            for (int j = 0; j < 4; j++)
                acc[i][j] = __builtin_amdgcn_mfma_f32_16x16x32_bf16(af[i], bfr[j], acc[i][j], 0, 0, 0);
    }

    // epilogue: C/D layout col=lane&15, row=quad*4+reg
#pragma unroll
    for (int i = 0; i < 4; i++) {
#pragma unroll
        for (int j = 0; j < 4; j++) {
            int col = bn + wc * 64 + j * 16 + lrow;
            float bv = (bias ? bias[col] : 0.f) + (bias2 ? bias2[col] : 0.f);
#pragma unroll
            for (int r = 0; r < 4; r++) {
                size_t row = (size_t)(bm + wr * 64 + i * 16 + quad * 4 + r);
                float v = acc[i][j][r] + bv;
                if (out_bf16) {
                    ((__hip_bfloat16*)C)[row * ldc + col] = __float2bfloat16(v);
                } else {
                    float* cp = (float*)C + row * ldc + col;
                    if (accum) *cp += v;
                    else       *cp = v;
                }
            }
        }
    }
}

static inline void mgemm(hipStream_t st, const __hip_bfloat16* A, int lda,
                         const __hip_bfloat16* Bt, int ldb,
                         const float* bias, const float* bias2,
                         void* C, int ldc, int M, int N, int K,
                         int out_bf16, int accum)
{
    dim3 grid(M / 128, N / 128);
    mgemm_kernel<<<grid, 256, 0, st>>>(A, lda, Bt, ldb, bias, bias2, C, ldc, K, out_bf16, accum);
}

// ================= small fp32 GEMM (stage-3 MLP only) =================
__global__ __launch_bounds__(256) void gemm_kernel(
    const float* __restrict__ A, int lda,
    const float* __restrict__ B, int ldb,
    const float* __restrict__ bias,
    float* __restrict__ C, int ldc,
    int K, int act)
{
    __shared__ float As[32][68];
    __shared__ float Bs[32][68];
    const int tid = threadIdx.x;
    const int bm = blockIdx.x * 64;
    const int bn = blockIdx.y * 64;
    const int tm = (tid & 15) * 4;
    const int tn = (tid >> 4) * 4;
    float acc[4][4] = {};

    for (int k0 = 0; k0 < K; k0 += 32) {
#pragma unroll
        for (int p = 0; p < 2; p++) {
            int lin = p * 256 + tid;
            int ar = lin >> 3;
            int ac = (lin & 7) << 2;
            float4 av = *(const float4*)(A + (size_t)(bm + ar) * lda + (k0 + ac));
            As[ac + 0][ar] = av.x;
            As[ac + 1][ar] = av.y;
            As[ac + 2][ar] = av.z;
            As[ac + 3][ar] = av.w;
            int br = lin >> 4;
            int bc = (lin & 15) << 2;
            *(float4*)&Bs[br][bc] = *(const float4*)(B + (size_t)(k0 + br) * ldb + (bn + bc));
        }
        __syncthreads();
#pragma unroll
        for (int k = 0; k < 32; k++) {
            float4 a4 = *(const float4*)&As[k][tm];
            float4 b4 = *(const float4*)&Bs[k][tn];
            float av[4] = {a4.x, a4.y, a4.z, a4.w};
            float bv[4] = {b4.x, b4.y, b4.z, b4.w};
#pragma unroll
            for (int i = 0; i < 4; i++)
#pragma unroll
                for (int j = 0; j < 4; j++)
                    acc[i][j] += av[i] * bv[j];
        }
        __syncthreads();
    }
#pragma unroll
    for (int i = 0; i < 4; i++) {
        size_t row = (size_t)(bm + tm + i);
#pragma unroll
        for (int j = 0; j < 4; j++) {
            int col = bn + tn + j;
            float val = acc[i][j] + (bias ? bias[col] : 0.f);
            if (act == 1) val = fmaxf(val, 0.f);
            C[row * ldc + col] = val;
        }
    }
}

// ================= weight prep =================
// W[n_et,128,128] (i,k,c) -> Bt[(i*128+c)][k] bf16
__global__ void prep_bcat_kernel(const float* __restrict__ W, __hip_bfloat16* __restrict__ Bt)
{
    int idx = blockIdx.x * blockDim.x + threadIdx.x;
    int i = idx >> 14;
    int k = (idx >> 7) & 127;
    int c = idx & 127;
    Bt[((size_t)(i * 128 + c)) * 128 + k] = __float2bfloat16(W[idx]);
}

// rz cat: Wt[n][k] (n<256,k<256): k<128 -> wih[k][n], else whh[k-128][n]; bias[n]=bih[n]+bhh[n]
__global__ void prep_rz_kernel(const float* __restrict__ wih, const float* __restrict__ whh,
                               const float* __restrict__ bih, const float* __restrict__ bhh,
                               __hip_bfloat16* __restrict__ Wt, float* __restrict__ bias)
{
    int idx = blockIdx.x * blockDim.x + threadIdx.x;   // 65536
    int n = idx >> 8;
    int k = idx & 255;
    float v = (k < 128) ? wih[k * 384 + n] : whh[(k - 128) * 384 + n];
    Wt[idx] = __float2bfloat16(v);
    if (k == 0) bias[n] = bih[n] + bhh[n];
}

// n-gate: Wt[n][k] = w[k*384 + 256 + n], 128x128
__global__ void prep_n_kernel(const float* __restrict__ w, __hip_bfloat16* __restrict__ Wt)
{
    int idx = blockIdx.x * blockDim.x + threadIdx.x;   // 16384
    int n = idx >> 7;
    int k = idx & 127;
    Wt[idx] = __float2bfloat16(w[k * 384 + 256 + n]);
}

// generic transpose: w[K][Nc] row-major -> Wt[Nc][K] bf16
__global__ void prep_t_kernel(const float* __restrict__ w, __hip_bfloat16* __restrict__ Wt,
                              int K, int Nc)
{
    int idx = blockIdx.x * blockDim.x + threadIdx.x;   // Nc*K
    int n = idx / K;
    int k = idx - n * K;
    Wt[idx] = __float2bfloat16(w[k * Nc + n]);
}

__global__ void f2b_kernel(const float* __restrict__ f, __hip_bfloat16* __restrict__ b)
{
    int idx = blockIdx.x * blockDim.x + threadIdx.x;
    b[idx] = __float2bfloat16(f[idx]);
}

// ================= CSR build =================
__global__ void hist_kernel(const int* __restrict__ dst, int E, int* __restrict__ counts)
{
    int e = blockIdx.x * blockDim.x + threadIdx.x;
    if (e < E) atomicAdd(&counts[dst[e]], 1);
}

__global__ void scan1_kernel(const int* __restrict__ counts, int* __restrict__ local_ex,
                             int* __restrict__ partial)
{
    __shared__ int s[256];
    int t = threadIdx.x;
    int i = blockIdx.x * 256 + t;
    int v = counts[i];
    s[t] = v;
    __syncthreads();
    for (int off = 1; off < 256; off <<= 1) {
        int x = 0;
        if (t >= off) x = s[t - off];
        __syncthreads();
        if (t >= off) s[t] += x;
        __syncthreads();
    }
    local_ex[i] = s[t] - v;
    if (t == 255) partial[blockIdx.x] = s[255];
}

__global__ void scan2_kernel(int* __restrict__ partial, int nb, int* __restrict__ indptr_last, int E)
{
    __shared__ int s[256];
    int t = threadIdx.x;
    int v = (t < nb) ? partial[t] : 0;
    s[t] = v;
    __syncthreads();
    for (int off = 1; off < 256; off <<= 1) {
        int x = 0;
        if (t >= off) x = s[t - off];
        __syncthreads();
        if (t >= off) s[t] += x;
        __syncthreads();
    }
    if (t < nb) partial[t] = s[t] - v;
    if (t == 0) *indptr_last = E;
}

__global__ void scan3_kernel(int* __restrict__ indptr, const int* __restrict__ partial)
{
    int i = blockIdx.x * 256 + threadIdx.x;
    indptr[i] += partial[blockIdx.x];
}

__global__ void copy_int_kernel(const int* __restrict__ a, int* __restrict__ b)
{
    int i = blockIdx.x * blockDim.x + threadIdx.x;
    b[i] = a[i];
}

__global__ void fill_kernel(const int* __restrict__ src, const int* __restrict__ dst,
                            const int* __restrict__ et, int E,
                            int* __restrict__ cursor, int* __restrict__ packed)
{
    int e = blockIdx.x * blockDim.x + threadIdx.x;
    if (e >= E) return;
    int pos = atomicAdd(&cursor[dst[e]], 1);
    packed[pos] = src[e] | (et[e] << 20);
}

// ================= CSR gather: ah[v][0:128] = bf16( sum tcat[src, et*128+c] ) =================
__global__ __launch_bounds__(128) void gather_kernel(
    const __hip_bfloat16* __restrict__ tcat, int stride,
    const int* __restrict__ indptr, const int* __restrict__ packed,
    __hip_bfloat16* __restrict__ ah)
{
    int v = blockIdx.x;
    int c = threadIdx.x;
    int beg = indptr[v], end = indptr[v + 1];
    float acc = 0.f;
    for (int j = beg; j < end; j++) {
        int p = packed[j];
        int srcn = p & 0xFFFFF;
        int et = p >> 20;
        acc += __bfloat162float(tcat[(size_t)srcn * stride + et * 128 + c]);
    }
    ah[(size_t)v * 256 + c] = __float2bfloat16(acc);
}

// ================= elementwise =================
// feat -> h fp32 (zero-padded) + ah h-part bf16
__global__ void pad_kernel(const float* __restrict__ f, float* __restrict__ h,
                           __hip_bfloat16* __restrict__ ah, int Fin)
{
    int idx = blockIdx.x * blockDim.x + threadIdx.x;   // N*128
    int c = idx & 127;
    int v = idx >> 7;
    float val = (c < Fin) ? f[(size_t)v * Fin + c] : 0.f;
    h[idx] = val;
    ah[(size_t)v * 256 + 128 + c] = __float2bfloat16(val);
}

// GRU gate: h = (1-z)*tanh(in + r*hn) + z*h ; also refresh ah h-part
__global__ void gru_gate_kernel(const float* __restrict__ rz, const float* __restrict__ inb,
                                const float* __restrict__ hnb, float* __restrict__ h,
                                __hip_bfloat16* __restrict__ ah)
{
    int idx = blockIdx.x * blockDim.x + threadIdx.x;   // N*128
    int c = idx & 127;
    int v = idx >> 7;
    float r = sigmoidf_(rz[(size_t)v * 256 + c]);
    float z = sigmoidf_(rz[(size_t)v * 256 + 128 + c]);
    float n = tanhf(inb[idx] + r * hnb[idx]);
    float hv = (1.f - z) * n + z * h[idx];
    h[idx] = hv;
    ah[(size_t)v * 256 + 128 + c] = __float2bfloat16(hv);
}

// o = sigmoid(u)*v ; optional bf16 copy
__global__ void sigmul_kernel(const float* __restrict__ u, const float* __restrict__ v,
                              float* __restrict__ o, __hip_bfloat16* __restrict__ ob)
{
    int idx = blockIdx.x * blockDim.x + threadIdx.x;
    float val = sigmoidf_(u[idx]) * v[idx];
    o[idx] = val;
    if (ob) ob[idx] = __float2bfloat16(val);
}

__global__ void pool_kernel(const float* __restrict__ r2, float* __restrict__ pooled)
{
    int s = blockIdx.x;
    int c = threadIdx.x;
    const float* base = r2 + (size_t)(2 * s) * PER * 128;
    float acc = 0.f;
    for (int i = 0; i < PER; i++) acc += base[(size_t)i * 128 + c];
    pooled[s * 128 + c] = acc;
}

__global__ void out_kernel(const float* __restrict__ x2, const float* __restrict__ wo,
                           const float* __restrict__ bo, float* __restrict__ out)
{
    int row = blockIdx.x;
    int t = threadIdx.x;
    float s = x2[row * 128 + t] * wo[t] + x2[row * 128 + 64 + t] * wo[64 + t];
#pragma unroll
    for (int off = 32; off; off >>= 1) s += __shfl_down(s, off);
    if (t == 0) out[row] = s + bo[0];
}

struct GGParams {
    const float *W, *b, *wih, *whh, *bih, *bhh, *iw, *ib, *jw, *jb;
};

struct WsPtrs {
    float* h;                 // [N,128] fp32
    __hip_bfloat16* ah;       // [N,256] bf16: cols 0..127 = a, 128..255 = h
    float* G;                 // 4.5*n128 fp32 scratch (tcat bf16 / rz,in,hn)
    float* r1; __hip_bfloat16* r1b;
    __hip_bfloat16* featb;
    __hip_bfloat16 *bcat_t, *rzw_t, *wnin_t, *wnhn_t, *iwh_t, *iwf_t, *jw_t;
    float* rzbias;
    int *indptr, *cursor, *partial, *packed;
    float *pooled, *x1, *x2;
};

static void run_stage(hipStream_t st, const float* featS, const __hip_bfloat16* featS_b, int Fin,
                      const int* src, const int* dst, const int* et, int E, int n_et,
                      const GGParams& p, const WsPtrs& w,
                      float* rout, __hip_bfloat16* rout_b)
{
    const int N = N_NODES;
    const size_t n128 = (size_t)N * 128;
    const int stride = n_et * 128;
    __hip_bfloat16* tcat = (__hip_bfloat16*)w.G;
    float* rz  = w.G;                  // [N,256] (after tcat dead)
    float* inb = w.G + 2 * n128;
    float* hnb = w.G + 3 * n128;

    // --- weight prep ---
    prep_bcat_kernel<<<(n_et * 16384) / 256, 256, 0, st>>>(p.W, w.bcat_t);
    prep_rz_kernel<<<65536 / 256, 256, 0, st>>>(p.wih, p.whh, p.bih, p.bhh, w.rzw_t, w.rzbias);
    prep_n_kernel<<<64, 256, 0, st>>>(p.wih, w.wnin_t);
    prep_n_kernel<<<64, 256, 0, st>>>(p.whh, w.wnhn_t);
    prep_t_kernel<<<16384 / 256, 256, 0, st>>>(p.iw, w.iwh_t, 128, 128);
    prep_t_kernel<<<(Fin * 128) / 256, 256, 0, st>>>(p.iw + 128 * 128, w.iwf_t, Fin, 128);
    prep_t_kernel<<<16384 / 256, 256, 0, st>>>(p.jw, w.jw_t, 128, 128);

    // --- CSR build (by dst) ---
    hipMemsetAsync(w.cursor, 0, N * sizeof(int), st);
    hist_kernel<<<(E + 255) / 256, 256, 0, st>>>(dst, E, w.cursor);
    scan1_kernel<<<SCAN_BLOCKS, 256, 0, st>>>(w.cursor, w.indptr, w.partial);
    scan2_kernel<<<1, 256, 0, st>>>(w.partial, SCAN_BLOCKS, w.indptr + N, E);
    scan3_kernel<<<SCAN_BLOCKS, 256, 0, st>>>(w.indptr, w.partial);
    copy_int_kernel<<<SCAN_BLOCKS, 256, 0, st>>>(w.indptr, w.cursor);
    fill_kernel<<<(E + 255) / 256, 256, 0, st>>>(src, dst, et, E, w.cursor, w.packed);

    pad_kernel<<<(N * 128) / 256, 256, 0, st>>>(featS, w.h, w.ah, Fin);

    for (int step = 0; step < 2; step++) {
        // tcat[N, n_et*128] = h @ Wcat + b   (bf16 out)
        mgemm(st, w.ah + 128, 256, w.bcat_t, 128, p.b, nullptr,
              tcat, stride, N, stride, 128, 1, 0);
        gather_kernel<<<N, 128, 0, st>>>(tcat, stride, w.indptr, w.packed, w.ah);
        // rz = [a,h] @ [wih_rz;whh_rz] + (bih+bhh)    K=256, N=256
        mgemm(st, w.ah, 256, w.rzw_t, 256, w.rzbias, nullptr, rz, 256, N, 256, 256, 0, 0);
        // in = a@wih_n + bih_n ; hn = h@whh_n + bhh_n
        mgemm(st, w.ah, 256,       w.wnin_t, 128, p.bih + 256, nullptr, inb, 128, N, 128, 128, 0, 0);
        mgemm(st, w.ah + 128, 256, w.wnhn_t, 128, p.bhh + 256, nullptr, hnb, 128, N, 128, 128, 0, 0);
        gru_gate_kernel<<<(N * 128) / 256, 256, 0, st>>>(rz, inb, hnb, w.h, w.ah);
    }

    // readout: rout = sigmoid(h@iw_h + feat@iw_f + ib) * (h@jw + jb)
    float* u = w.G;
    float* v = w.G + n128;
    mgemm(st, w.ah + 128, 256, w.iwh_t, 128, p.ib, nullptr, u, 128, N, 128, 128, 0, 0);
    mgemm(st, featS_b, Fin,    w.iwf_t, Fin, nullptr, nullptr, u, 128, N, 128, Fin, 0, 1);
    mgemm(st, w.ah + 128, 256, w.jw_t,  128, p.jb, nullptr, v, 128, N, 128, 128, 0, 0);
    sigmul_kernel<<<(N * 128) / 256, 256, 0, st>>>(u, v, rout, rout_b);
}

extern "C" void kernel_launch(void* const* d_in, const int* in_sizes, int n_in,
                              void* d_out, int out_size, void* d_ws, size_t ws_size,
                              hipStream_t stream)
{
    const float* feat    = (const float*)d_in[0];
    const int*   bi_src  = (const int*)d_in[1];
    const int*   bi_dst  = (const int*)d_in[2];
    const int*   bi_et   = (const int*)d_in[3];
    const int*   knn_src = (const int*)d_in[4];
    const int*   knn_dst = (const int*)d_in[5];
    const int*   knn_et  = (const int*)d_in[6];

    GGParams s1 { (const float*)d_in[8],  (const float*)d_in[9],  (const float*)d_in[10],
                  (const float*)d_in[11], (const float*)d_in[12], (const float*)d_in[13],
                  (const float*)d_in[14], (const float*)d_in[15], (const float*)d_in[16],
                  (const float*)d_in[17] };
    GGParams s2 { (const float*)d_in[18], (const float*)d_in[19], (const float*)d_in[20],
                  (const float*)d_in[21], (const float*)d_in[22], (const float*)d_in[23],
                  (const float*)d_in[24], (const float*)d_in[25], (const float*)d_in[26],
                  (const float*)d_in[27] };
    const float* w0 = (const float*)d_in[28];
    const float* b0 = (const float*)d_in[29];
    const float* w1 = (const float*)d_in[30];
    const float* b1 = (const float*)d_in[31];
    const float* wo = (const float*)d_in[32];
    const float* bo = (const float*)d_in[33];

    const int N = N_NODES;
    const size_t n128 = (size_t)N * 128;

    float* ws = (float*)d_ws;
    WsPtrs w;
    size_t off = 0;
    w.h     = ws + off;                        off += n128;
    w.ah    = (__hip_bfloat16*)(ws + off);     off += n128;            // N*256 bf16
    w.G     = ws + off;                        off += (9 * n128) / 2;  // 4.5*n128
    w.r1    = ws + off;                        off += n128;
    w.r1b   = (__hip_bfloat16*)(ws + off);     off += n128 / 2;
    w.featb = (__hip_bfloat16*)(ws + off);     off += n128 / 4;        // N*64 bf16
    w.bcat_t = (__hip_bfloat16*)(ws + off);    off += 9 * 16384 / 2;
    w.rzw_t  = (__hip_bfloat16*)(ws + off);    off += 65536 / 2;
    w.wnin_t = (__hip_bfloat16*)(ws + off);    off += 16384 / 2;
    w.wnhn_t = (__hip_bfloat16*)(ws + off);    off += 16384 / 2;
    w.iwh_t  = (__hip_bfloat16*)(ws + off);    off += 16384 / 2;
    w.iwf_t  = (__hip_bfloat16*)(ws + off);    off += 16384 / 2;
    w.jw_t   = (__hip_bfloat16*)(ws + off);    off += 16384 / 2;
    w.rzbias = ws + off;                       off += 256;
    w.indptr  = (int*)(ws + off);              off += 50180;
    w.cursor  = (int*)(ws + off);              off += N;
    w.partial = (int*)(ws + off);              off += 256;
    w.packed  = (int*)(ws + off);              off += E_KNN;
    w.pooled  = ws + off;                      off += 64 * 128;
    w.x1      = ws + off;                      off += 64 * 256;
    w.x2      = ws + off;                      off += 64 * 128;

    // feat -> bf16 once (for stage-1 readout accum GEMM)
    f2b_kernel<<<(N * 64) / 256, 256, 0, stream>>>(feat, w.featb);

    // Stage 1: bond graph (5 etypes), Fin=64
    run_stage(stream, feat, w.featb, 64, bi_src, bi_dst, bi_et, E_BI, 5, s1, w,
              w.r1, w.r1b);
    // Stage 2: knn graph (9 etypes), feat = stage-1 readout
    float* rout2 = w.G + 2 * n128;     // free region after last gate
    run_stage(stream, w.r1, w.r1b, 128, knn_src, knn_dst, knn_et, E_KNN, 9, s2, w,
              rout2, nullptr);

    // Stage 3: ligand pooling + MLP (fp32, tiny)
    pool_kernel<<<64, 128, 0, stream>>>(rout2, w.pooled);
    {
        dim3 g1(1, 4);
        gemm_kernel<<<g1, 256, 0, stream>>>(w.pooled, 128, w0, 256, b0, w.x1, 256, 128, 1);
        dim3 g2(1, 2);
        gemm_kernel<<<g2, 256, 0, stream>>>(w.x1, 256, w1, 128, b1, w.x2, 128, 256, 1);
    }
    out_kernel<<<64, 64, 0, stream>>>(w.x2, wo, bo, (float*)d_out);
}

// Round 4
// 1123.909 us; speedup vs baseline: 4.1079x; 1.0596x over previous
//
#include <hip/hip_runtime.h>
#include <hip/hip_bf16.h>

#define N_NODES 50176
#define PER 392
#define E_BI (N_NODES * 4)      // 200704
#define E_KNN (N_NODES * 16)    // 802816
#define SCAN_BLOCKS 196         // 196*256 == 50176

typedef __attribute__((ext_vector_type(8))) short short8;
typedef __attribute__((ext_vector_type(4))) float float4v;
typedef unsigned int uint;
typedef unsigned short ushort;

__device__ __forceinline__ float sigmoidf_(float x) { return 1.f / (1.f + __expf(-x)); }
__device__ __forceinline__ ushort f2bu(float x) {
    __hip_bfloat16 t = __float2bfloat16(x);
    return *reinterpret_cast<ushort*>(&t);
}

// ================= bf16 MFMA GEMM =================
// C[M,Ncols] = A[M,K]_bf16 @ Bt^T + bias ; Bt[n][k] (transposed B), ldb.
// Tile 128x128, 256 threads = 4 waves, 4x4 mfma_16x16x32 per wave.
// M,Ncols multiples of 128 (Ncols via grid.y), K multiple of 32.
__global__ __launch_bounds__(256) void mgemm_kernel(
    const __hip_bfloat16* __restrict__ A, int lda,
    const __hip_bfloat16* __restrict__ Bt, int ldb,
    const float* __restrict__ bias,
    void* __restrict__ C, int ldc, int K,
    int out_bf16, int accum)
{
    __shared__ short As[128 * 32];
    __shared__ short Bs[128 * 32];
    const int tid = threadIdx.x;
    const int bm = blockIdx.x * 128;
    const int bn = blockIdx.y * 128;
    const int wave = tid >> 6, lane = tid & 63;
    const int quad = lane >> 4, lrow = lane & 15;
    const int wr = wave & 1, wc = wave >> 1;

    const short* Ap = (const short*)A;
    const short* Bp = (const short*)Bt;

    float4v acc[4][4] = {};

    for (int k0 = 0; k0 < K; k0 += 32) {
        __syncthreads();
#pragma unroll
        for (int p = 0; p < 2; p++) {
            int lin = p * 256 + tid;      // 0..511
            int r = lin >> 2;             // 0..127
            int kc = (lin & 3) * 8;       // 0,8,16,24
            *(short8*)&As[r * 32 + kc] = *(const short8*)(Ap + (size_t)(bm + r) * lda + k0 + kc);
            *(short8*)&Bs[r * 32 + kc] = *(const short8*)(Bp + (size_t)(bn + r) * ldb + k0 + kc);
        }
        __syncthreads();
        short8 af[4], bfr[4];
#pragma unroll
        for (int i = 0; i < 4; i++)
            af[i] = *(const short8*)&As[(wr * 64 + i * 16 + lrow) * 32 + quad * 8];
#pragma unroll
        for (int j = 0; j < 4; j++)
            bfr[j] = *(const short8*)&Bs[(wc * 64 + j * 16 + lrow) * 32 + quad * 8];
#pragma unroll
        for (int i = 0; i < 4; i++)
#pragma unroll
            for (int j = 0; j < 4; j++)
                acc[i][j] = __builtin_amdgcn_mfma_f32_16x16x32_bf16(af[i], bfr[j], acc[i][j], 0, 0, 0);
    }

#pragma unroll
    for (int i = 0; i < 4; i++) {
#pragma unroll
        for (int j = 0; j < 4; j++) {
            int col = bn + wc * 64 + j * 16 + lrow;
            float bv = bias ? bias[col] : 0.f;
#pragma unroll
            for (int r = 0; r < 4; r++) {
                size_t row = (size_t)(bm + wr * 64 + i * 16 + quad * 4 + r);
                float v = acc[i][j][r] + bv;
                if (out_bf16) {
                    ((__hip_bfloat16*)C)[row * ldc + col] = __float2bfloat16(v);
                } else {
                    float* cp = (float*)C + row * ldc + col;
                    if (accum) *cp += v;
                    else       *cp = v;
                }
            }
        }
    }
}

static inline void mgemm(hipStream_t st, const __hip_bfloat16* A, int lda,
                         const __hip_bfloat16* Bt, int ldb, const float* bias,
                         void* C, int ldc, int M, int Ncols, int K,
                         int out_bf16, int accum)
{
    dim3 grid(M / 128, Ncols / 128);
    mgemm_kernel<<<grid, 256, 0, st>>>(A, lda, Bt, ldb, bias, C, ldc, K, out_bf16, accum);
}

// ================= small fp32 GEMM (stage-3 MLP only) =================
__global__ __launch_bounds__(256) void gemm_kernel(
    const float* __restrict__ A, int lda,
    const float* __restrict__ B, int ldb,
    const float* __restrict__ bias,
    float* __restrict__ C, int ldc,
    int K, int act)
{
    __shared__ float As[32][68];
    __shared__ float Bs[32][68];
    const int tid = threadIdx.x;
    const int bm = blockIdx.x * 64;
    const int bn = blockIdx.y * 64;
    const int tm = (tid & 15) * 4;
    const int tn = (tid >> 4) * 4;
    float acc[4][4] = {};

    for (int k0 = 0; k0 < K; k0 += 32) {
#pragma unroll
        for (int p = 0; p < 2; p++) {
            int lin = p * 256 + tid;
            int ar = lin >> 3;
            int ac = (lin & 7) << 2;
            float4 av = *(const float4*)(A + (size_t)(bm + ar) * lda + (k0 + ac));
            As[ac + 0][ar] = av.x;
            As[ac + 1][ar] = av.y;
            As[ac + 2][ar] = av.z;
            As[ac + 3][ar] = av.w;
            int br = lin >> 4;
            int bc = (lin & 15) << 2;
            *(float4*)&Bs[br][bc] = *(const float4*)(B + (size_t)(k0 + br) * ldb + (bn + bc));
        }
        __syncthreads();
#pragma unroll
        for (int k = 0; k < 32; k++) {
            float4 a4 = *(const float4*)&As[k][tm];
            float4 b4 = *(const float4*)&Bs[k][tn];
            float av[4] = {a4.x, a4.y, a4.z, a4.w};
            float bv[4] = {b4.x, b4.y, b4.z, b4.w};
#pragma unroll
            for (int i = 0; i < 4; i++)
#pragma unroll
                for (int j = 0; j < 4; j++)
                    acc[i][j] += av[i] * bv[j];
        }
        __syncthreads();
    }
#pragma unroll
    for (int i = 0; i < 4; i++) {
        size_t row = (size_t)(bm + tm + i);
#pragma unroll
        for (int j = 0; j < 4; j++) {
            int col = bn + tn + j;
            float val = acc[i][j] + (bias ? bias[col] : 0.f);
            if (act == 1) val = fmaxf(val, 0.f);
            C[row * ldc + col] = val;
        }
    }
}

// ================= weight prep =================
// Message weights: Bt[c][kk], kk<net*128: W[et][k][c]; net*128<=kk<net*128+net: b[j][c]; else 0
__global__ void prep_bcat2_kernel(const float* __restrict__ W, const float* __restrict__ b,
                                  __hip_bfloat16* __restrict__ Bt, int net, int stride)
{
    int idx = blockIdx.x * blockDim.x + threadIdx.x;   // 128*stride
    int c = idx / stride;
    int kk = idx - c * stride;
    float val;
    if (kk < net * 128) {
        int et = kk >> 7, k = kk & 127;
        val = W[et * 16384 + k * 128 + c];
    } else {
        int j = kk - net * 128;
        val = (j < net) ? b[j * 128 + c] : 0.f;
    }
    Bt[idx] = __float2bfloat16(val);
}

// GRU fused: Bt[512][256]; cols(n): 0..255 rz, 256..383 in, 384..511 hn
__global__ void prep_gru_kernel(const float* __restrict__ wih, const float* __restrict__ whh,
                                const float* __restrict__ bih, const float* __restrict__ bhh,
                                __hip_bfloat16* __restrict__ Bt, float* __restrict__ bias)
{
    int idx = blockIdx.x * blockDim.x + threadIdx.x;   // 131072
    int n = idx >> 8;
    int k = idx & 255;
    float val;
    if (n < 256)      val = (k < 128) ? wih[k * 384 + n] : whh[(k - 128) * 384 + n];
    else if (n < 384) val = (k < 128) ? wih[k * 384 + n] : 0.f;            // n in 256..383 -> wih col n
    else              val = (k < 128) ? 0.f : whh[(k - 128) * 384 + (n - 128)];
    Bt[idx] = __float2bfloat16(val);
    if (k == 0) bias[n] = (n < 256) ? bih[n] + bhh[n] : (n < 384 ? bih[n] : bhh[n - 128]);
}

// Readout part 1: Bt[256][128]; n<128: iw h-rows, n>=128: jw
__global__ void prep_ro1_kernel(const float* __restrict__ iw, const float* __restrict__ jw,
                                const float* __restrict__ ib, const float* __restrict__ jb,
                                __hip_bfloat16* __restrict__ Bt, float* __restrict__ bias)
{
    int idx = blockIdx.x * blockDim.x + threadIdx.x;   // 32768
    int n = idx >> 7;
    int k = idx & 127;
    float val = (n < 128) ? iw[k * 128 + n] : jw[k * 128 + (n - 128)];
    Bt[idx] = __float2bfloat16(val);
    if (k == 0) bias[n] = (n < 128) ? ib[n] : jb[n - 128];
}

// Readout part 2 (feat): Bt[128][Fin] = iw[(128+k)*128 + n]
__global__ void prep_ro2_kernel(const float* __restrict__ iw, __hip_bfloat16* __restrict__ Bt,
                                int Fin)
{
    int idx = blockIdx.x * blockDim.x + threadIdx.x;   // 128*Fin
    int n = idx / Fin;
    int k = idx - n * Fin;
    Bt[idx] = __float2bfloat16(iw[(128 + k) * 128 + n]);
}

__global__ void f2b_kernel(const float* __restrict__ f, __hip_bfloat16* __restrict__ b)
{
    int idx = blockIdx.x * blockDim.x + threadIdx.x;
    b[idx] = __float2bfloat16(f[idx]);
}

// ================= CSR build =================
__global__ void hist_kernel(const int* __restrict__ dst, int E, int* __restrict__ counts)
{
    int e = blockIdx.x * blockDim.x + threadIdx.x;
    if (e < E) atomicAdd(&counts[dst[e]], 1);
}

__global__ void scan1_kernel(const int* __restrict__ counts, int* __restrict__ local_ex,
                             int* __restrict__ partial)
{
    __shared__ int s[256];
    int t = threadIdx.x;
    int i = blockIdx.x * 256 + t;
    int v = counts[i];
    s[t] = v;
    __syncthreads();
    for (int off = 1; off < 256; off <<= 1) {
        int x = 0;
        if (t >= off) x = s[t - off];
        __syncthreads();
        if (t >= off) s[t] += x;
        __syncthreads();
    }
    local_ex[i] = s[t] - v;
    if (t == 255) partial[blockIdx.x] = s[255];
}

__global__ void scan2_kernel(int* __restrict__ partial, int nb, int* __restrict__ indptr_last, int E)
{
    __shared__ int s[256];
    int t = threadIdx.x;
    int v = (t < nb) ? partial[t] : 0;
    s[t] = v;
    __syncthreads();
    for (int off = 1; off < 256; off <<= 1) {
        int x = 0;
        if (t >= off) x = s[t - off];
        __syncthreads();
        if (t >= off) s[t] += x;
        __syncthreads();
    }
    if (t < nb) partial[t] = s[t] - v;
    if (t == 0) *indptr_last = E;
}

__global__ void scan3_kernel(int* __restrict__ indptr, const int* __restrict__ partial)
{
    int i = blockIdx.x * 256 + threadIdx.x;
    indptr[i] += partial[blockIdx.x];
}

__global__ void copy_int_kernel(const int* __restrict__ a, int* __restrict__ b)
{
    int i = blockIdx.x * blockDim.x + threadIdx.x;
    b[i] = a[i];
}

__global__ void fill_kernel(const int* __restrict__ src, const int* __restrict__ dst,
                            const int* __restrict__ et, int E,
                            int* __restrict__ cursor, int* __restrict__ packed)
{
    int e = blockIdx.x * blockDim.x + threadIdx.x;
    if (e >= E) return;
    int pos = atomicAdd(&cursor[dst[e]], 1);
    packed[pos] = src[e] | (et[e] << 20);
}

// ================= per-etype neighbor aggregation =================
// s[v, et*128 + c] = bf16( sum_{e in in(v), etype=et} h_bf16[src_e, c] )
// s[v, NET*128 + j] = cnt_j (j<NET), else 0.  One wave per node; lane l = channels 2l,2l+1.
template<int NET>
__global__ __launch_bounds__(256) void agg_kernel(
    const uint* __restrict__ ahp,     // (uint*)ah: rows of 128 uints, h-half at +64
    const int* __restrict__ indptr, const int* __restrict__ packed,
    ushort* __restrict__ s, int stride_s)
{
    int v = blockIdx.x * 4 + (threadIdx.x >> 6);
    int l = threadIdx.x & 63;
    int beg = indptr[v], end = indptr[v + 1];
    float aLo[NET], aHi[NET];
    int cnt[NET];
#pragma unroll
    for (int i = 0; i < NET; i++) { aLo[i] = 0.f; aHi[i] = 0.f; cnt[i] = 0; }

    for (int j = beg; j < end; j++) {
        int p = __builtin_amdgcn_readfirstlane(packed[j]);
        int srcn = p & 0xFFFFF;
        int et = p >> 20;
        uint u = ahp[(size_t)srcn * 128 + 64 + l];
        float lo = __uint_as_float(u << 16);
        float hi = __uint_as_float(u & 0xFFFF0000u);
#pragma unroll
        for (int i = 0; i < NET; i++) {
            if (et == i) { aLo[i] += lo; aHi[i] += hi; cnt[i]++; }
        }
    }

    uint* srow = (uint*)(s + (size_t)v * stride_s);
#pragma unroll
    for (int i = 0; i < NET; i++) {
        uint pk = (uint)f2bu(aLo[i]) | ((uint)f2bu(aHi[i]) << 16);
        srow[i * 64 + l] = pk;
    }
    if (l < 32) {
        float cv = 0.f;
#pragma unroll
        for (int i = 0; i < NET; i++) if (l == i) cv = (float)cnt[i];
        s[(size_t)v * stride_s + NET * 128 + l] = f2bu(cv);
    }
}

// ================= elementwise (all 4-wide) =================
// feat -> h fp32 (zero-padded) + ah h-part bf16
__global__ void pad_kernel(const float* __restrict__ f, float* __restrict__ h,
                           uint* __restrict__ ahp, int Fin)
{
    int idx = blockIdx.x * blockDim.x + threadIdx.x;   // N*32
    int v = idx >> 5;
    int c = (idx & 31) * 4;
    float4 val = make_float4(0.f, 0.f, 0.f, 0.f);
    if (c < Fin) val = *(const float4*)(f + (size_t)v * Fin + c);
    *(float4*)(h + (size_t)v * 128 + c) = val;
    uint2 pk;
    pk.x = (uint)f2bu(val.x) | ((uint)f2bu(val.y) << 16);
    pk.y = (uint)f2bu(val.z) | ((uint)f2bu(val.w) << 16);
    *(uint2*)(ahp + (size_t)v * 128 + 64 + c / 2) = pk;
}

// GRU gate from fused rzin[N,512]: h = (1-z)*tanh(in + r*hn) + z*h ; refresh ah h-part
__global__ void gru_gate_kernel(const float* __restrict__ rzin, float* __restrict__ h,
                                uint* __restrict__ ahp)
{
    int idx = blockIdx.x * blockDim.x + threadIdx.x;   // N*32
    int v = idx >> 5;
    int c = (idx & 31) * 4;
    const float* base = rzin + (size_t)v * 512;
    float4 r4 = *(const float4*)(base + c);
    float4 z4 = *(const float4*)(base + 128 + c);
    float4 i4 = *(const float4*)(base + 256 + c);
    float4 n4 = *(const float4*)(base + 384 + c);
    float4 h4 = *(const float4*)(h + (size_t)v * 128 + c);
    float4 o;
    {
        float r = sigmoidf_(r4.x), z = sigmoidf_(z4.x);
        o.x = (1.f - z) * tanhf(i4.x + r * n4.x) + z * h4.x;
        r = sigmoidf_(r4.y); z = sigmoidf_(z4.y);
        o.y = (1.f - z) * tanhf(i4.y + r * n4.y) + z * h4.y;
        r = sigmoidf_(r4.z); z = sigmoidf_(z4.z);
        o.z = (1.f - z) * tanhf(i4.z + r * n4.z) + z * h4.z;
        r = sigmoidf_(r4.w); z = sigmoidf_(z4.w);
        o.w = (1.f - z) * tanhf(i4.w + r * n4.w) + z * h4.w;
    }
    *(float4*)(h + (size_t)v * 128 + c) = o;
    uint2 pk;
    pk.x = (uint)f2bu(o.x) | ((uint)f2bu(o.y) << 16);
    pk.y = (uint)f2bu(o.z) | ((uint)f2bu(o.w) << 16);
    *(uint2*)(ahp + (size_t)v * 128 + 64 + c / 2) = pk;
}

// o = sigmoid(uv[:,0:128]) * uv[:,128:256]; optional bf16 copy
__global__ void sigmul_kernel(const float* __restrict__ uv, float* __restrict__ o,
                              uint* __restrict__ obp)
{
    int idx = blockIdx.x * blockDim.x + threadIdx.x;   // N*32
    int v = idx >> 5;
    int c = (idx & 31) * 4;
    float4 u4 = *(const float4*)(uv + (size_t)v * 256 + c);
    float4 v4 = *(const float4*)(uv + (size_t)v * 256 + 128 + c);
    float4 r;
    r.x = sigmoidf_(u4.x) * v4.x;
    r.y = sigmoidf_(u4.y) * v4.y;
    r.z = sigmoidf_(u4.z) * v4.z;
    r.w = sigmoidf_(u4.w) * v4.w;
    *(float4*)(o + (size_t)v * 128 + c) = r;
    if (obp) {
        uint2 pk;
        pk.x = (uint)f2bu(r.x) | ((uint)f2bu(r.y) << 16);
        pk.y = (uint)f2bu(r.z) | ((uint)f2bu(r.w) << 16);
        *(uint2*)(obp + (size_t)v * 64 + c / 2) = pk;
    }
}

__global__ void pool_kernel(const float* __restrict__ r2, float* __restrict__ pooled)
{
    int s = blockIdx.x;
    int c = threadIdx.x;
    const float* base = r2 + (size_t)(2 * s) * PER * 128;
    float acc = 0.f;
    for (int i = 0; i < PER; i++) acc += base[(size_t)i * 128 + c];
    pooled[s * 128 + c] = acc;
}

__global__ void out_kernel(const float* __restrict__ x2, const float* __restrict__ wo,
                           const float* __restrict__ bo, float* __restrict__ out)
{
    int row = blockIdx.x;
    int t = threadIdx.x;
    float s = x2[row * 128 + t] * wo[t] + x2[row * 128 + 64 + t] * wo[64 + t];
#pragma unroll
    for (int off = 32; off; off >>= 1) s += __shfl_down(s, off);
    if (t == 0) out[row] = s + bo[0];
}

struct GGParams {
    const float *W, *b, *wih, *whh, *bih, *bhh, *iw, *ib, *jw, *jb;
};

struct WsPtrs {
    float* h;                 // [N,128] fp32 GRU state
    __hip_bfloat16* ah;       // [N,256] bf16: [a | h]
    float* G;                 // N*592 floats scratch: s / rzin / uv / rout2
    float* r1;                // stage-1 readout fp32
    __hip_bfloat16* r1b;      // stage-1 readout bf16 [N,128]
    __hip_bfloat16* featb;    // feat bf16 [N,64]
    __hip_bfloat16 *bcatB, *gruB, *ro1B, *ro2B;
    float *gruBias, *ro1Bias;
    int *indptr, *cursor, *partial, *packed;
    float *pooled, *x1, *x2;
};

template<int NET>
static void run_stage(hipStream_t st, const float* featS, const __hip_bfloat16* featb, int Fin,
                      const int* src, const int* dst, const int* et, int E,
                      const GGParams& p, const WsPtrs& w,
                      float* rout, __hip_bfloat16* rout_b)
{
    const int N = N_NODES;
    const size_t n128 = (size_t)N * 128;
    const int stride_s = NET * 128 + 32;
    ushort* sbuf = (ushort*)w.G;
    float* rzin = w.G;                 // [N,512] (s dead after message GEMM)
    float* uv   = w.G;                 // [N,256] (rzin dead after last gate)
    uint* ahp = (uint*)w.ah;

    // --- weight prep ---
    prep_bcat2_kernel<<<(128 * stride_s) / 256, 256, 0, st>>>(p.W, p.b, w.bcatB, NET, stride_s);
    prep_gru_kernel<<<131072 / 256, 256, 0, st>>>(p.wih, p.whh, p.bih, p.bhh, w.gruB, w.gruBias);
    prep_ro1_kernel<<<32768 / 256, 256, 0, st>>>(p.iw, p.jw, p.ib, p.jb, w.ro1B, w.ro1Bias);
    prep_ro2_kernel<<<(128 * Fin) / 256, 256, 0, st>>>(p.iw, w.ro2B, Fin);

    // --- CSR build (by dst) ---
    hipMemsetAsync(w.cursor, 0, N * sizeof(int), st);
    hist_kernel<<<(E + 255) / 256, 256, 0, st>>>(dst, E, w.cursor);
    scan1_kernel<<<SCAN_BLOCKS, 256, 0, st>>>(w.cursor, w.indptr, w.partial);
    scan2_kernel<<<1, 256, 0, st>>>(w.partial, SCAN_BLOCKS, w.indptr + N, E);
    scan3_kernel<<<SCAN_BLOCKS, 256, 0, st>>>(w.indptr, w.partial);
    copy_int_kernel<<<SCAN_BLOCKS, 256, 0, st>>>(w.indptr, w.cursor);
    fill_kernel<<<(E + 255) / 256, 256, 0, st>>>(src, dst, et, E, w.cursor, w.packed);

    pad_kernel<<<(N * 32) / 256, 256, 0, st>>>(featS, w.h, ahp, Fin);

    for (int step = 0; step < 2; step++) {
        // s[v, et] = per-etype neighbor sums (+ counts) from L3-resident h
        agg_kernel<NET><<<N / 4, 256, 0, st>>>(ahp, w.indptr, w.packed, sbuf, stride_s);
        // a = s @ Wstack (+ cnt-encoded per-edge biases) -> ah[:,0:128] bf16
        mgemm(st, (const __hip_bfloat16*)sbuf, stride_s, w.bcatB, stride_s, nullptr,
              w.ah, 256, N, 128, stride_s, 1, 0);
        // rz|in|hn = [a,h] @ Wbig + bias  -> rzin[N,512]
        mgemm(st, w.ah, 256, w.gruB, 256, w.gruBias, rzin, 512, N, 512, 256, 0, 0);
        gru_gate_kernel<<<(N * 32) / 256, 256, 0, st>>>(rzin, w.h, ahp);
    }

    // readout: uv = [ h@iwh + feat@iwf + ib | h@jw + jb ]
    mgemm(st, w.ah + 128, 256, w.ro1B, 128, w.ro1Bias, uv, 256, N, 256, 128, 0, 0);
    mgemm(st, featb, Fin, w.ro2B, Fin, nullptr, uv, 256, N, 128, Fin, 0, 1);
    sigmul_kernel<<<(N * 32) / 256, 256, 0, st>>>(uv, rout, (uint*)rout_b);
}

extern "C" void kernel_launch(void* const* d_in, const int* in_sizes, int n_in,
                              void* d_out, int out_size, void* d_ws, size_t ws_size,
                              hipStream_t stream)
{
    const float* feat    = (const float*)d_in[0];
    const int*   bi_src  = (const int*)d_in[1];
    const int*   bi_dst  = (const int*)d_in[2];
    const int*   bi_et   = (const int*)d_in[3];
    const int*   knn_src = (const int*)d_in[4];
    const int*   knn_dst = (const int*)d_in[5];
    const int*   knn_et  = (const int*)d_in[6];

    GGParams s1 { (const float*)d_in[8],  (const float*)d_in[9],  (const float*)d_in[10],
                  (const float*)d_in[11], (const float*)d_in[12], (const float*)d_in[13],
                  (const float*)d_in[14], (const float*)d_in[15], (const float*)d_in[16],
                  (const float*)d_in[17] };
    GGParams s2 { (const float*)d_in[18], (const float*)d_in[19], (const float*)d_in[20],
                  (const float*)d_in[21], (const float*)d_in[22], (const float*)d_in[23],
                  (const float*)d_in[24], (const float*)d_in[25], (const float*)d_in[26],
                  (const float*)d_in[27] };
    const float* w0 = (const float*)d_in[28];
    const float* b0 = (const float*)d_in[29];
    const float* w1 = (const float*)d_in[30];
    const float* b1 = (const float*)d_in[31];
    const float* wo = (const float*)d_in[32];
    const float* bo = (const float*)d_in[33];

    const int N = N_NODES;
    const size_t n128 = (size_t)N * 128;

    float* ws = (float*)d_ws;
    WsPtrs w;
    size_t off = 0;
    w.h     = ws + off;                        off += n128;
    w.ah    = (__hip_bfloat16*)(ws + off);     off += n128;           // N*256 bf16
    w.G     = ws + off;                        off += (size_t)N * 592; // s_knn / rzin / uv
    w.r1    = ws + off;                        off += n128;
    w.r1b   = (__hip_bfloat16*)(ws + off);     off += n128 / 2;
    w.featb = (__hip_bfloat16*)(ws + off);     off += n128 / 4;
    w.bcatB = (__hip_bfloat16*)(ws + off);     off += 128 * 1184 / 2;
    w.gruB  = (__hip_bfloat16*)(ws + off);     off += 131072 / 2;
    w.ro1B  = (__hip_bfloat16*)(ws + off);     off += 32768 / 2;
    w.ro2B  = (__hip_bfloat16*)(ws + off);     off += 16384 / 2;
    w.gruBias = ws + off;                      off += 512;
    w.ro1Bias = ws + off;                      off += 256;
    w.indptr  = (int*)(ws + off);              off += N + 4;
    w.cursor  = (int*)(ws + off);              off += N;
    w.partial = (int*)(ws + off);              off += 256;
    w.packed  = (int*)(ws + off);              off += E_KNN;
    w.pooled  = ws + off;                      off += 64 * 128;
    w.x1      = ws + off;                      off += 64 * 256;
    w.x2      = ws + off;                      off += 64 * 128;

    // feat -> bf16 once (stage-1 readout accum GEMM input)
    f2b_kernel<<<(N * 64) / 256, 256, 0, stream>>>(feat, w.featb);

    // Stage 1: bond graph (5 etypes), Fin=64
    run_stage<5>(stream, feat, w.featb, 64, bi_src, bi_dst, bi_et, E_BI, s1, w,
                 w.r1, w.r1b);
    // Stage 2: knn graph (9 etypes), feat = stage-1 readout
    float* rout2 = w.G + 2 * n128;   // after uv within G
    run_stage<9>(stream, w.r1, w.r1b, 128, knn_src, knn_dst, knn_et, E_KNN, s2, w,
                 rout2, nullptr);

    // Stage 3: ligand pooling + MLP (fp32, tiny)
    pool_kernel<<<64, 128, 0, stream>>>(rout2, w.pooled);
    {
        dim3 g1(1, 4);
        gemm_kernel<<<g1, 256, 0, stream>>>(w.pooled, 128, w0, 256, b0, w.x1, 256, 128, 1);
        dim3 g2(1, 2);
        gemm_kernel<<<g2, 256, 0, stream>>>(w.x1, 256, w1, 128, b1, w.x2, 128, 256, 1);
    }
    out_kernel<<<64, 64, 0, stream>>>(w.x2, wo, bo, (float*)d_out);
}

// Round 5
// 966.187 us; speedup vs baseline: 4.7785x; 1.1632x over previous
//
#include <hip/hip_runtime.h>
#include <hip/hip_bf16.h>

#define N_NODES 50176
#define PER 392
#define E_BI (N_NODES * 4)      // 200704
#define E_KNN (N_NODES * 16)    // 802816

typedef __attribute__((ext_vector_type(8))) short short8;
typedef __attribute__((ext_vector_type(4))) float float4v;
typedef unsigned int uint;
typedef unsigned short ushort;

__device__ __forceinline__ float sigmoidf_(float x) { return 1.f / (1.f + __expf(-x)); }
__device__ __forceinline__ ushort f2bu(float x) {
    __hip_bfloat16 t = __float2bfloat16(x);
    return *reinterpret_cast<ushort*>(&t);
}

// ================= fused aggregate + per-etype transform =================
// a[v,:] = bf16( sum_et ( sum_{e in in(v),et} h_bf16[src_e,:] ) @ W_et + cnt_et * b_et )
// Edges CSR-sorted by key dst*NET+et. One block = 128 node rows, all 128 out cols.
// fp32 register accumulation of neighbor sums, rounded once to bf16 (same as r4).
template<int NET>
__global__ __launch_bounds__(256) void msg_kernel(
    const uint* __restrict__ ahp,          // ah rows of 128 uints; h-half at +64
    const int* __restrict__ indptr,        // [N*NET+1]
    const int* __restrict__ elist,         // src node per edge, sorted by (dst,et)
    const __hip_bfloat16* __restrict__ Bt, // [128 cols][STRIDE] prepped weights+bias rows
    ushort* __restrict__ aout)             // ah base (ushort); write cols 0..127, ld 256
{
    constexpr int STRIDE = NET * 128 + 32;
    __shared__ ushort As[4 * 128 * 32];    // current etype's A tile, chunk-major [ch][r][32]
    __shared__ ushort Acnt[128 * 32];      // counts tile (bias chunk)
    __shared__ ushort Bs[4 * 128 * 32];    // current etype's W tile  [ch][n][32]

    const int tid = threadIdx.x;
    const int bm = blockIdx.x * 128;
    const int wave = tid >> 6, lane = tid & 63;
    const int quad = lane >> 4, lrow = lane & 15;
    const int wr = wave & 1, wc = wave >> 1;

    const int r = tid >> 1;                // node row in tile
    const int half = tid & 1;              // channel half (64 ch each)
    const int v = bm + r;

    uint* AsU = (uint*)As;
    uint* AcntU = (uint*)Acnt;
    const ushort* BtU = (const ushort*)Bt;

    // zero counts tile (cols >= NET stay 0)
#pragma unroll
    for (int q = 0; q < 8; q++) AcntU[q * 256 + tid] = 0u;

    float4v acc[4][4] = {};

    for (int et = 0; et < NET; et++) {
        const int key = v * NET + et;
        const int beg = indptr[key], end = indptr[key + 1];
        float av[64];
#pragma unroll
        for (int i = 0; i < 64; i++) av[i] = 0.f;

        for (int j = beg; j < end; j++) {
            int src = elist[j];
            const uint4* hp = (const uint4*)(ahp + (size_t)src * 128 + 64 + half * 32);
#pragma unroll
            for (int q = 0; q < 8; q++) {
                uint4 u = hp[q];
                av[q * 8 + 0] += __uint_as_float(u.x << 16);
                av[q * 8 + 1] += __uint_as_float(u.x & 0xFFFF0000u);
                av[q * 8 + 2] += __uint_as_float(u.y << 16);
                av[q * 8 + 3] += __uint_as_float(u.y & 0xFFFF0000u);
                av[q * 8 + 4] += __uint_as_float(u.z << 16);
                av[q * 8 + 5] += __uint_as_float(u.z & 0xFFFF0000u);
                av[q * 8 + 6] += __uint_as_float(u.w << 16);
                av[q * 8 + 7] += __uint_as_float(u.w & 0xFFFF0000u);
            }
        }

        __syncthreads();   // previous etype's MFMA reads of As/Bs complete
        // write As (bf16, chunk-major)
#pragma unroll
        for (int cl = 0; cl < 2; cl++) {
            int ch = half * 2 + cl;
#pragma unroll
            for (int u = 0; u < 16; u++) {
                float lo = av[cl * 32 + 2 * u], hi = av[cl * 32 + 2 * u + 1];
                AsU[ch * 2048 + r * 16 + u] = (uint)f2bu(lo) | ((uint)f2bu(hi) << 16);
            }
        }
        if (half == 0) Acnt[r * 32 + et] = f2bu((float)(end - beg));
        // stage this etype's W tile (all 4 k-chunks)
#pragma unroll
        for (int p = 0; p < 8; p++) {
            int u = p * 256 + tid;                 // 0..2047 16B-units
            int ch = u >> 9, n = (u >> 2) & 127, kg = u & 3;
            *(short8*)&Bs[ch * 4096 + n * 32 + kg * 8] =
                *(const short8*)(BtU + (size_t)n * STRIDE + et * 128 + ch * 32 + kg * 8);
        }
        __syncthreads();
#pragma unroll
        for (int ch = 0; ch < 4; ch++) {
            short8 af[4], bfr[4];
#pragma unroll
            for (int i = 0; i < 4; i++)
                af[i] = *(const short8*)&As[ch * 4096 + (wr * 64 + i * 16 + lrow) * 32 + quad * 8];
#pragma unroll
            for (int j = 0; j < 4; j++)
                bfr[j] = *(const short8*)&Bs[ch * 4096 + (wc * 64 + j * 16 + lrow) * 32 + quad * 8];
#pragma unroll
            for (int i = 0; i < 4; i++)
#pragma unroll
                for (int j = 0; j < 4; j++)
                    acc[i][j] = __builtin_amdgcn_mfma_f32_16x16x32_bf16(af[i], bfr[j], acc[i][j], 0, 0, 0);
        }
    }

    // bias via counts chunk (K=32)
    __syncthreads();
#pragma unroll
    for (int p = 0; p < 2; p++) {
        int u = p * 256 + tid;                     // 0..511
        int n = u >> 2, kg = u & 3;
        *(short8*)&Bs[n * 32 + kg * 8] =
            *(const short8*)(BtU + (size_t)n * STRIDE + NET * 128 + kg * 8);
    }
    __syncthreads();
    {
        short8 af[4], bfr[4];
#pragma unroll
        for (int i = 0; i < 4; i++)
            af[i] = *(const short8*)&Acnt[(wr * 64 + i * 16 + lrow) * 32 + quad * 8];
#pragma unroll
        for (int j = 0; j < 4; j++)
            bfr[j] = *(const short8*)&Bs[(wc * 64 + j * 16 + lrow) * 32 + quad * 8];
#pragma unroll
        for (int i = 0; i < 4; i++)
#pragma unroll
            for (int j = 0; j < 4; j++)
                acc[i][j] = __builtin_amdgcn_mfma_f32_16x16x32_bf16(af[i], bfr[j], acc[i][j], 0, 0, 0);
    }

    // epilogue: a -> ah cols 0..127 (bf16)
#pragma unroll
    for (int i = 0; i < 4; i++) {
#pragma unroll
        for (int j = 0; j < 4; j++) {
            int col = wc * 64 + j * 16 + lrow;
#pragma unroll
            for (int rr = 0; rr < 4; rr++) {
                size_t row = (size_t)(bm + wr * 64 + i * 16 + quad * 4 + rr);
                aout[row * 256 + col] = f2bu(acc[i][j][rr]);
            }
        }
    }
}

// ================= bf16 MFMA GEMM (GRU / readout) =================
__global__ __launch_bounds__(256) void mgemm_kernel(
    const __hip_bfloat16* __restrict__ A, int lda,
    const __hip_bfloat16* __restrict__ Bt, int ldb,
    const float* __restrict__ bias,
    void* __restrict__ C, int ldc, int K,
    int out_bf16, int accum)
{
    __shared__ short As[128 * 32];
    __shared__ short Bs[128 * 32];
    const int tid = threadIdx.x;
    const int bm = blockIdx.x * 128;
    const int bn = blockIdx.y * 128;
    const int wave = tid >> 6, lane = tid & 63;
    const int quad = lane >> 4, lrow = lane & 15;
    const int wr = wave & 1, wc = wave >> 1;

    const short* Ap = (const short*)A;
    const short* Bp = (const short*)Bt;

    float4v acc[4][4] = {};

    for (int k0 = 0; k0 < K; k0 += 32) {
        __syncthreads();
#pragma unroll
        for (int p = 0; p < 2; p++) {
            int lin = p * 256 + tid;
            int r = lin >> 2;
            int kc = (lin & 3) * 8;
            *(short8*)&As[r * 32 + kc] = *(const short8*)(Ap + (size_t)(bm + r) * lda + k0 + kc);
            *(short8*)&Bs[r * 32 + kc] = *(const short8*)(Bp + (size_t)(bn + r) * ldb + k0 + kc);
        }
        __syncthreads();
        short8 af[4], bfr[4];
#pragma unroll
        for (int i = 0; i < 4; i++)
            af[i] = *(const short8*)&As[(wr * 64 + i * 16 + lrow) * 32 + quad * 8];
#pragma unroll
        for (int j = 0; j < 4; j++)
            bfr[j] = *(const short8*)&Bs[(wc * 64 + j * 16 + lrow) * 32 + quad * 8];
#pragma unroll
        for (int i = 0; i < 4; i++)
#pragma unroll
            for (int j = 0; j < 4; j++)
                acc[i][j] = __builtin_amdgcn_mfma_f32_16x16x32_bf16(af[i], bfr[j], acc[i][j], 0, 0, 0);
    }

#pragma unroll
    for (int i = 0; i < 4; i++) {
#pragma unroll
        for (int j = 0; j < 4; j++) {
            int col = bn + wc * 64 + j * 16 + lrow;
            float bv = bias ? bias[col] : 0.f;
#pragma unroll
            for (int r = 0; r < 4; r++) {
                size_t row = (size_t)(bm + wr * 64 + i * 16 + quad * 4 + r);
                float v = acc[i][j][r] + bv;
                if (out_bf16) {
                    ((__hip_bfloat16*)C)[row * ldc + col] = __float2bfloat16(v);
                } else {
                    float* cp = (float*)C + row * ldc + col;
                    if (accum) *cp += v;
                    else       *cp = v;
                }
            }
        }
    }
}

static inline void mgemm(hipStream_t st, const __hip_bfloat16* A, int lda,
                         const __hip_bfloat16* Bt, int ldb, const float* bias,
                         void* C, int ldc, int M, int Ncols, int K,
                         int out_bf16, int accum)
{
    dim3 grid(M / 128, Ncols / 128);
    mgemm_kernel<<<grid, 256, 0, st>>>(A, lda, Bt, ldb, bias, C, ldc, K, out_bf16, accum);
}

// ================= small fp32 GEMM (stage-3 MLP only) =================
__global__ __launch_bounds__(256) void gemm_kernel(
    const float* __restrict__ A, int lda,
    const float* __restrict__ B, int ldb,
    const float* __restrict__ bias,
    float* __restrict__ C, int ldc,
    int K, int act)
{
    __shared__ float As[32][68];
    __shared__ float Bs[32][68];
    const int tid = threadIdx.x;
    const int bm = blockIdx.x * 64;
    const int bn = blockIdx.y * 64;
    const int tm = (tid & 15) * 4;
    const int tn = (tid >> 4) * 4;
    float acc[4][4] = {};

    for (int k0 = 0; k0 < K; k0 += 32) {
#pragma unroll
        for (int p = 0; p < 2; p++) {
            int lin = p * 256 + tid;
            int ar = lin >> 3;
            int ac = (lin & 7) << 2;
            float4 av = *(const float4*)(A + (size_t)(bm + ar) * lda + (k0 + ac));
            As[ac + 0][ar] = av.x;
            As[ac + 1][ar] = av.y;
            As[ac + 2][ar] = av.z;
            As[ac + 3][ar] = av.w;
            int br = lin >> 4;
            int bc = (lin & 15) << 2;
            *(float4*)&Bs[br][bc] = *(const float4*)(B + (size_t)(k0 + br) * ldb + (bn + bc));
        }
        __syncthreads();
#pragma unroll
        for (int k = 0; k < 32; k++) {
            float4 a4 = *(const float4*)&As[k][tm];
            float4 b4 = *(const float4*)&Bs[k][tn];
            float av[4] = {a4.x, a4.y, a4.z, a4.w};
            float bv[4] = {b4.x, b4.y, b4.z, b4.w};
#pragma unroll
            for (int i = 0; i < 4; i++)
#pragma unroll
                for (int j = 0; j < 4; j++)
                    acc[i][j] += av[i] * bv[j];
        }
        __syncthreads();
    }
#pragma unroll
    for (int i = 0; i < 4; i++) {
        size_t row = (size_t)(bm + tm + i);
#pragma unroll
        for (int j = 0; j < 4; j++) {
            int col = bn + tn + j;
            float val = acc[i][j] + (bias ? bias[col] : 0.f);
            if (act == 1) val = fmaxf(val, 0.f);
            C[row * ldc + col] = val;
        }
    }
}

// ================= weight prep =================
__global__ void prep_bcat2_kernel(const float* __restrict__ W, const float* __restrict__ b,
                                  __hip_bfloat16* __restrict__ Bt, int net, int stride)
{
    int idx = blockIdx.x * blockDim.x + threadIdx.x;   // 128*stride
    int c = idx / stride;
    int kk = idx - c * stride;
    float val;
    if (kk < net * 128) {
        int et = kk >> 7, k = kk & 127;
        val = W[et * 16384 + k * 128 + c];
    } else {
        int j = kk - net * 128;
        val = (j < net) ? b[j * 128 + c] : 0.f;
    }
    Bt[idx] = __float2bfloat16(val);
}

__global__ void prep_gru_kernel(const float* __restrict__ wih, const float* __restrict__ whh,
                                const float* __restrict__ bih, const float* __restrict__ bhh,
                                __hip_bfloat16* __restrict__ Bt, float* __restrict__ bias)
{
    int idx = blockIdx.x * blockDim.x + threadIdx.x;   // 131072
    int n = idx >> 8;
    int k = idx & 255;
    float val;
    if (n < 256)      val = (k < 128) ? wih[k * 384 + n] : whh[(k - 128) * 384 + n];
    else if (n < 384) val = (k < 128) ? wih[k * 384 + n] : 0.f;
    else              val = (k < 128) ? 0.f : whh[(k - 128) * 384 + (n - 128)];
    Bt[idx] = __float2bfloat16(val);
    if (k == 0) bias[n] = (n < 256) ? bih[n] + bhh[n] : (n < 384 ? bih[n] : bhh[n - 128]);
}

__global__ void prep_ro1_kernel(const float* __restrict__ iw, const float* __restrict__ jw,
                                const float* __restrict__ ib, const float* __restrict__ jb,
                                __hip_bfloat16* __restrict__ Bt, float* __restrict__ bias)
{
    int idx = blockIdx.x * blockDim.x + threadIdx.x;   // 32768
    int n = idx >> 7;
    int k = idx & 127;
    float val = (n < 128) ? iw[k * 128 + n] : jw[k * 128 + (n - 128)];
    Bt[idx] = __float2bfloat16(val);
    if (k == 0) bias[n] = (n < 128) ? ib[n] : jb[n - 128];
}

__global__ void prep_ro2_kernel(const float* __restrict__ iw, __hip_bfloat16* __restrict__ Bt,
                                int Fin)
{
    int idx = blockIdx.x * blockDim.x + threadIdx.x;   // 128*Fin
    int n = idx / Fin;
    int k = idx - n * Fin;
    Bt[idx] = __float2bfloat16(iw[(128 + k) * 128 + n]);
}

__global__ void f2b_kernel(const float* __restrict__ f, __hip_bfloat16* __restrict__ b)
{
    int idx = blockIdx.x * blockDim.x + threadIdx.x;
    b[idx] = __float2bfloat16(f[idx]);
}

// ================= CSR build (key = dst*NET + et) =================
__global__ void histk_kernel(const int* __restrict__ dst, const int* __restrict__ et,
                             int E, int net, int* __restrict__ counts)
{
    int e = blockIdx.x * blockDim.x + threadIdx.x;
    if (e < E) atomicAdd(&counts[dst[e] * net + et[e]], 1);
}

__global__ void scan1_kernel(const int* __restrict__ counts, int* __restrict__ local_ex,
                             int* __restrict__ partial)
{
    __shared__ int s[256];
    int t = threadIdx.x;
    int i = blockIdx.x * 256 + t;
    int v = counts[i];
    s[t] = v;
    __syncthreads();
    for (int off = 1; off < 256; off <<= 1) {
        int x = 0;
        if (t >= off) x = s[t - off];
        __syncthreads();
        if (t >= off) s[t] += x;
        __syncthreads();
    }
    local_ex[i] = s[t] - v;
    if (t == 255) partial[blockIdx.x] = s[255];
}

// level-2 scan over up to 2048 partials (serial 8 per thread)
__global__ void scan2b_kernel(int* __restrict__ partial, int nb, int* __restrict__ last, int E)
{
    __shared__ int s[256];
    int t = threadIdx.x;
    int loc[8];
    int sum = 0;
#pragma unroll
    for (int q = 0; q < 8; q++) {
        int idx = t * 8 + q;
        int v = (idx < nb) ? partial[idx] : 0;
        loc[q] = sum; sum += v;
    }
    s[t] = sum;
    __syncthreads();
    for (int off = 1; off < 256; off <<= 1) {
        int x = 0;
        if (t >= off) x = s[t - off];
        __syncthreads();
        if (t >= off) s[t] += x;
        __syncthreads();
    }
    int excl = s[t] - sum;
#pragma unroll
    for (int q = 0; q < 8; q++) {
        int idx = t * 8 + q;
        if (idx < nb) partial[idx] = excl + loc[q];
    }
    if (t == 0) *last = E;
}

__global__ void scan3_kernel(int* __restrict__ indptr, const int* __restrict__ partial)
{
    int i = blockIdx.x * 256 + threadIdx.x;
    indptr[i] += partial[blockIdx.x];
}

__global__ void copy_int_kernel(const int* __restrict__ a, int* __restrict__ b)
{
    int i = blockIdx.x * blockDim.x + threadIdx.x;
    b[i] = a[i];
}

__global__ void fillk_kernel(const int* __restrict__ src, const int* __restrict__ dst,
                             const int* __restrict__ et, int E, int net,
                             int* __restrict__ cursor, int* __restrict__ elist)
{
    int e = blockIdx.x * blockDim.x + threadIdx.x;
    if (e >= E) return;
    int pos = atomicAdd(&cursor[dst[e] * net + et[e]], 1);
    elist[pos] = src[e];
}

// ================= elementwise =================
__global__ void pad_kernel(const float* __restrict__ f, float* __restrict__ h,
                           uint* __restrict__ ahp, int Fin)
{
    int idx = blockIdx.x * blockDim.x + threadIdx.x;   // N*32
    int v = idx >> 5;
    int c = (idx & 31) * 4;
    float4 val = make_float4(0.f, 0.f, 0.f, 0.f);
    if (c < Fin) val = *(const float4*)(f + (size_t)v * Fin + c);
    *(float4*)(h + (size_t)v * 128 + c) = val;
    uint2 pk;
    pk.x = (uint)f2bu(val.x) | ((uint)f2bu(val.y) << 16);
    pk.y = (uint)f2bu(val.z) | ((uint)f2bu(val.w) << 16);
    *(uint2*)(ahp + (size_t)v * 128 + 64 + c / 2) = pk;
}

__global__ void gru_gate_kernel(const float* __restrict__ rzin, float* __restrict__ h,
                                uint* __restrict__ ahp)
{
    int idx = blockIdx.x * blockDim.x + threadIdx.x;   // N*32
    int v = idx >> 5;
    int c = (idx & 31) * 4;
    const float* base = rzin + (size_t)v * 512;
    float4 r4 = *(const float4*)(base + c);
    float4 z4 = *(const float4*)(base + 128 + c);
    float4 i4 = *(const float4*)(base + 256 + c);
    float4 n4 = *(const float4*)(base + 384 + c);
    float4 h4 = *(const float4*)(h + (size_t)v * 128 + c);
    float4 o;
    {
        float r = sigmoidf_(r4.x), z = sigmoidf_(z4.x);
        o.x = (1.f - z) * tanhf(i4.x + r * n4.x) + z * h4.x;
        r = sigmoidf_(r4.y); z = sigmoidf_(z4.y);
        o.y = (1.f - z) * tanhf(i4.y + r * n4.y) + z * h4.y;
        r = sigmoidf_(r4.z); z = sigmoidf_(z4.z);
        o.z = (1.f - z) * tanhf(i4.z + r * n4.z) + z * h4.z;
        r = sigmoidf_(r4.w); z = sigmoidf_(z4.w);
        o.w = (1.f - z) * tanhf(i4.w + r * n4.w) + z * h4.w;
    }
    *(float4*)(h + (size_t)v * 128 + c) = o;
    uint2 pk;
    pk.x = (uint)f2bu(o.x) | ((uint)f2bu(o.y) << 16);
    pk.y = (uint)f2bu(o.z) | ((uint)f2bu(o.w) << 16);
    *(uint2*)(ahp + (size_t)v * 128 + 64 + c / 2) = pk;
}

__global__ void sigmul_kernel(const float* __restrict__ uv, float* __restrict__ o,
                              uint* __restrict__ obp)
{
    int idx = blockIdx.x * blockDim.x + threadIdx.x;   // N*32
    int v = idx >> 5;
    int c = (idx & 31) * 4;
    float4 u4 = *(const float4*)(uv + (size_t)v * 256 + c);
    float4 v4 = *(const float4*)(uv + (size_t)v * 256 + 128 + c);
    float4 r;
    r.x = sigmoidf_(u4.x) * v4.x;
    r.y = sigmoidf_(u4.y) * v4.y;
    r.z = sigmoidf_(u4.z) * v4.z;
    r.w = sigmoidf_(u4.w) * v4.w;
    *(float4*)(o + (size_t)v * 128 + c) = r;
    if (obp) {
        uint2 pk;
        pk.x = (uint)f2bu(r.x) | ((uint)f2bu(r.y) << 16);
        pk.y = (uint)f2bu(r.z) | ((uint)f2bu(r.w) << 16);
        *(uint2*)(obp + (size_t)v * 64 + c / 2) = pk;
    }
}

__global__ void pool_kernel(const float* __restrict__ r2, float* __restrict__ pooled)
{
    int s = blockIdx.x;
    int c = threadIdx.x;
    const float* base = r2 + (size_t)(2 * s) * PER * 128;
    float acc = 0.f;
    for (int i = 0; i < PER; i++) acc += base[(size_t)i * 128 + c];
    pooled[s * 128 + c] = acc;
}

__global__ void out_kernel(const float* __restrict__ x2, const float* __restrict__ wo,
                           const float* __restrict__ bo, float* __restrict__ out)
{
    int row = blockIdx.x;
    int t = threadIdx.x;
    float s = x2[row * 128 + t] * wo[t] + x2[row * 128 + 64 + t] * wo[64 + t];
#pragma unroll
    for (int off = 32; off; off >>= 1) s += __shfl_down(s, off);
    if (t == 0) out[row] = s + bo[0];
}

struct GGParams {
    const float *W, *b, *wih, *whh, *bih, *bhh, *iw, *ib, *jw, *jb;
};

struct WsPtrs {
    float* h;
    __hip_bfloat16* ah;       // [N,256] bf16: [a | h]
    float* G;                 // N*512 floats: rzin / uv / rout2
    float* r1;
    __hip_bfloat16* r1b;
    __hip_bfloat16* featb;
    __hip_bfloat16 *bcatB, *gruB, *ro1B, *ro2B;
    float *gruBias, *ro1Bias;
    int *indptr, *cursor, *partial, *elist;
    float *pooled, *x1, *x2;
};

template<int NET>
static void run_stage(hipStream_t st, const float* featS, const __hip_bfloat16* featb, int Fin,
                      const int* src, const int* dst, const int* et, int E,
                      const GGParams& p, const WsPtrs& w,
                      float* rout, __hip_bfloat16* rout_b)
{
    const int N = N_NODES;
    const size_t n128 = (size_t)N * 128;
    const int STRIDE = NET * 128 + 32;
    const int KN = N * NET;                 // multiple of 256
    float* rzin = w.G;
    float* uv   = w.G;
    uint* ahp = (uint*)w.ah;

    // --- weight prep ---
    prep_bcat2_kernel<<<(128 * STRIDE) / 256, 256, 0, st>>>(p.W, p.b, w.bcatB, NET, STRIDE);
    prep_gru_kernel<<<131072 / 256, 256, 0, st>>>(p.wih, p.whh, p.bih, p.bhh, w.gruB, w.gruBias);
    prep_ro1_kernel<<<32768 / 256, 256, 0, st>>>(p.iw, p.jw, p.ib, p.jb, w.ro1B, w.ro1Bias);
    prep_ro2_kernel<<<(128 * Fin) / 256, 256, 0, st>>>(p.iw, w.ro2B, Fin);

    // --- CSR build keyed by dst*NET+et ---
    hipMemsetAsync(w.cursor, 0, KN * sizeof(int), st);
    histk_kernel<<<(E + 255) / 256, 256, 0, st>>>(dst, et, E, NET, w.cursor);
    scan1_kernel<<<KN / 256, 256, 0, st>>>(w.cursor, w.indptr, w.partial);
    scan2b_kernel<<<1, 256, 0, st>>>(w.partial, KN / 256, w.indptr + KN, E);
    scan3_kernel<<<KN / 256, 256, 0, st>>>(w.indptr, w.partial);
    copy_int_kernel<<<KN / 256, 256, 0, st>>>(w.indptr, w.cursor);
    fillk_kernel<<<(E + 255) / 256, 256, 0, st>>>(src, dst, et, E, NET, w.cursor, w.elist);

    pad_kernel<<<(N * 32) / 256, 256, 0, st>>>(featS, w.h, ahp, Fin);

    for (int step = 0; step < 2; step++) {
        // fused aggregate + transform: a -> ah[:,0:128]
        msg_kernel<NET><<<N / 128, 256, 0, st>>>(ahp, w.indptr, w.elist, w.bcatB,
                                                 (ushort*)w.ah);
        // rz|in|hn = [a,h] @ Wbig + bias
        mgemm(st, w.ah, 256, w.gruB, 256, w.gruBias, rzin, 512, N, 512, 256, 0, 0);
        gru_gate_kernel<<<(N * 32) / 256, 256, 0, st>>>(rzin, w.h, ahp);
    }

    // readout
    mgemm(st, w.ah + 128, 256, w.ro1B, 128, w.ro1Bias, uv, 256, N, 256, 128, 0, 0);
    mgemm(st, featb, Fin, w.ro2B, Fin, nullptr, uv, 256, N, 128, Fin, 0, 1);
    sigmul_kernel<<<(N * 32) / 256, 256, 0, st>>>(uv, rout, (uint*)rout_b);
}

extern "C" void kernel_launch(void* const* d_in, const int* in_sizes, int n_in,
                              void* d_out, int out_size, void* d_ws, size_t ws_size,
                              hipStream_t stream)
{
    const float* feat    = (const float*)d_in[0];
    const int*   bi_src  = (const int*)d_in[1];
    const int*   bi_dst  = (const int*)d_in[2];
    const int*   bi_et   = (const int*)d_in[3];
    const int*   knn_src = (const int*)d_in[4];
    const int*   knn_dst = (const int*)d_in[5];
    const int*   knn_et  = (const int*)d_in[6];

    GGParams s1 { (const float*)d_in[8],  (const float*)d_in[9],  (const float*)d_in[10],
                  (const float*)d_in[11], (const float*)d_in[12], (const float*)d_in[13],
                  (const float*)d_in[14], (const float*)d_in[15], (const float*)d_in[16],
                  (const float*)d_in[17] };
    GGParams s2 { (const float*)d_in[18], (const float*)d_in[19], (const float*)d_in[20],
                  (const float*)d_in[21], (const float*)d_in[22], (const float*)d_in[23],
                  (const float*)d_in[24], (const float*)d_in[25], (const float*)d_in[26],
                  (const float*)d_in[27] };
    const float* w0 = (const float*)d_in[28];
    const float* b0 = (const float*)d_in[29];
    const float* w1 = (const float*)d_in[30];
    const float* b1 = (const float*)d_in[31];
    const float* wo = (const float*)d_in[32];
    const float* bo = (const float*)d_in[33];

    const int N = N_NODES;
    const size_t n128 = (size_t)N * 128;
    const int KNMAX = N * 9;               // 451584

    float* ws = (float*)d_ws;
    WsPtrs w;
    size_t off = 0;
    w.h     = ws + off;                        off += n128;
    w.ah    = (__hip_bfloat16*)(ws + off);     off += n128;
    w.G     = ws + off;                        off += 4 * n128;        // N*512
    w.r1    = ws + off;                        off += n128;
    w.r1b   = (__hip_bfloat16*)(ws + off);     off += n128 / 2;
    w.featb = (__hip_bfloat16*)(ws + off);     off += n128 / 4;
    w.bcatB = (__hip_bfloat16*)(ws + off);     off += 128 * 1184 / 2;
    w.gruB  = (__hip_bfloat16*)(ws + off);     off += 131072 / 2;
    w.ro1B  = (__hip_bfloat16*)(ws + off);     off += 32768 / 2;
    w.ro2B  = (__hip_bfloat16*)(ws + off);     off += 16384 / 2;
    w.gruBias = ws + off;                      off += 512;
    w.ro1Bias = ws + off;                      off += 256;
    w.indptr  = (int*)(ws + off);              off += KNMAX + 8;
    w.cursor  = (int*)(ws + off);              off += KNMAX;
    w.partial = (int*)(ws + off);              off += 2048;
    w.elist   = (int*)(ws + off);              off += E_KNN;
    w.pooled  = ws + off;                      off += 64 * 128;
    w.x1      = ws + off;                      off += 64 * 256;
    w.x2      = ws + off;                      off += 64 * 128;

    f2b_kernel<<<(N * 64) / 256, 256, 0, stream>>>(feat, w.featb);

    // Stage 1: bond graph (5 etypes), Fin=64
    run_stage<5>(stream, feat, w.featb, 64, bi_src, bi_dst, bi_et, E_BI, s1, w,
                 w.r1, w.r1b);
    // Stage 2: knn graph (9 etypes)
    float* rout2 = w.G + 2 * n128;
    run_stage<9>(stream, w.r1, w.r1b, 128, knn_src, knn_dst, knn_et, E_KNN, s2, w,
                 rout2, nullptr);

    // Stage 3: ligand pooling + MLP
    pool_kernel<<<64, 128, 0, stream>>>(rout2, w.pooled);
    {
        dim3 g1(1, 4);
        gemm_kernel<<<g1, 256, 0, stream>>>(w.pooled, 128, w0, 256, b0, w.x1, 256, 128, 1);
        dim3 g2(1, 2);
        gemm_kernel<<<g2, 256, 0, stream>>>(w.x1, 256, w1, 128, b1, w.x2, 128, 256, 1);
    }
    out_kernel<<<64, 64, 0, stream>>>(w.x2, wo, bo, (float*)d_out);
}

// Round 6
// 932.251 us; speedup vs baseline: 4.9524x; 1.0364x over previous
//
#include <hip/hip_runtime.h>
#include <hip/hip_bf16.h>

#define N_NODES 50176
#define PER 392
#define E_BI (N_NODES * 4)      // 200704
#define E_KNN (N_NODES * 16)    // 802816
#define E_TOT (E_BI + E_KNN)    // 1003520
#define KN_BI (N_NODES * 5)     // 250880
#define KN_TOT (N_NODES * 14)   // 702464  (5 bond + 9 knn etype keys)
#define AH_S 288                // ah row stride in shorts: [a(128) | h(128) | cnt(32)]
#define AH_U 144                // ... in uints

typedef __attribute__((ext_vector_type(8))) short short8;
typedef __attribute__((ext_vector_type(4))) float float4v;
typedef unsigned int uint;
typedef unsigned short ushort;

__device__ __forceinline__ float sigmoidf_(float x) { return 1.f / (1.f + __expf(-x)); }
__device__ __forceinline__ ushort f2bu(float x) {
    __hip_bfloat16 t = __float2bfloat16(x);
    return *reinterpret_cast<ushort*>(&t);
}

// ================= fused aggregate + per-etype transform (v3) =================
// a[v,:] = bf16( sum_et ( sum_{e in in(v),et} h_bf16[src_e,:] ) @ W_et )   (bias via GRU cnt cols)
// Block = 64 node rows, 256 threads: 4 threads per row (32 ch each), av[32] regs.
// 4 waves each compute 64x32 output (acc[4][2]); B from global in fragment order.
template<int NET>
__global__ __launch_bounds__(256) void msg_kernel(
    const uint* __restrict__ ahp,          // uint view of ah; h-half at +64, row stride AH_U
    const int* __restrict__ indptr,        // [N*NET+1] slice (values absolute into elist)
    const int* __restrict__ elist,
    const ushort* __restrict__ Bfrag,      // fragment-ordered weights
    ushort* __restrict__ aout)             // ah base; write cols 0..127, stride AH_S
{
    __shared__ ushort As[4][64][40];       // 20.5 KB, chunk-major, 80B rows (conflict-free)
    const int tid = threadIdx.x;
    const int bm = blockIdx.x * 64;
    const int wave = tid >> 6, lane = tid & 63;
    const int quad = lane >> 4, lrow = lane & 15;
    const int r = tid >> 2;                // node row 0..63
    const int qtr = tid & 3;               // channel quarter (= As chunk owned)
    const int v = bm + r;

    uint* AsU = (uint*)As;                 // [ch][r][20] uints

    float4v acc[4][2] = {};

    for (int et = 0; et < NET; et++) {
        const int beg = indptr[v * NET + et], end = indptr[v * NET + et + 1];
        float av[32];
#pragma unroll
        for (int i = 0; i < 32; i++) av[i] = 0.f;

        for (int j = beg; j < end; j++) {
            int src = elist[j];
            const uint4* hp = (const uint4*)(ahp + (size_t)src * AH_U + 64 + qtr * 16);
#pragma unroll
            for (int q = 0; q < 4; q++) {
                uint4 u = hp[q];
                av[q * 8 + 0] += __uint_as_float(u.x << 16);
                av[q * 8 + 1] += __uint_as_float(u.x & 0xFFFF0000u);
                av[q * 8 + 2] += __uint_as_float(u.y << 16);
                av[q * 8 + 3] += __uint_as_float(u.y & 0xFFFF0000u);
                av[q * 8 + 4] += __uint_as_float(u.z << 16);
                av[q * 8 + 5] += __uint_as_float(u.z & 0xFFFF0000u);
                av[q * 8 + 6] += __uint_as_float(u.w << 16);
                av[q * 8 + 7] += __uint_as_float(u.w & 0xFFFF0000u);
            }
        }

        __syncthreads();                   // previous etype's As reads complete
#pragma unroll
        for (int u = 0; u < 16; u++) {
            AsU[(qtr * 64 + r) * 20 + u] =
                (uint)f2bu(av[2 * u]) | ((uint)f2bu(av[2 * u + 1]) << 16);
        }
        __syncthreads();

#pragma unroll
        for (int ch = 0; ch < 4; ch++) {
            short8 af[4], bfr[2];
#pragma unroll
            for (int i = 0; i < 4; i++)
                af[i] = *(const short8*)&As[ch][i * 16 + lrow][quad * 8];
            const ushort* bp = Bfrag + ((size_t)(((et * 4 + ch) * 4 + wave) * 2) * 64 + lane) * 8;
            bfr[0] = *(const short8*)bp;
            bfr[1] = *(const short8*)(bp + 512);
#pragma unroll
            for (int i = 0; i < 4; i++)
#pragma unroll
                for (int j = 0; j < 2; j++)
                    acc[i][j] = __builtin_amdgcn_mfma_f32_16x16x32_bf16(af[i], bfr[j], acc[i][j], 0, 0, 0);
        }
    }

    // epilogue: a -> ah cols 0..127
#pragma unroll
    for (int i = 0; i < 4; i++) {
#pragma unroll
        for (int j = 0; j < 2; j++) {
            int col = wave * 32 + j * 16 + lrow;
#pragma unroll
            for (int rr = 0; rr < 4; rr++) {
                size_t row = (size_t)(bm + i * 16 + quad * 4 + rr);
                aout[row * AH_S + col] = f2bu(acc[i][j][rr]);
            }
        }
    }
}

// ================= bf16 MFMA GEMM (GRU / readout) =================
__global__ __launch_bounds__(256) void mgemm_kernel(
    const __hip_bfloat16* __restrict__ A, int lda,
    const __hip_bfloat16* __restrict__ Bt, int ldb,
    const float* __restrict__ bias,
    void* __restrict__ C, int ldc, int K,
    int out_bf16, int accum)
{
    __shared__ short As[128 * 32];
    __shared__ short Bs[128 * 32];
    const int tid = threadIdx.x;
    const int bm = blockIdx.x * 128;
    const int bn = blockIdx.y * 128;
    const int wave = tid >> 6, lane = tid & 63;
    const int quad = lane >> 4, lrow = lane & 15;
    const int wr = wave & 1, wc = wave >> 1;

    const short* Ap = (const short*)A;
    const short* Bp = (const short*)Bt;

    float4v acc[4][4] = {};

    for (int k0 = 0; k0 < K; k0 += 32) {
        __syncthreads();
#pragma unroll
        for (int p = 0; p < 2; p++) {
            int lin = p * 256 + tid;
            int r = lin >> 2;
            int kc = (lin & 3) * 8;
            *(short8*)&As[r * 32 + kc] = *(const short8*)(Ap + (size_t)(bm + r) * lda + k0 + kc);
            *(short8*)&Bs[r * 32 + kc] = *(const short8*)(Bp + (size_t)(bn + r) * ldb + k0 + kc);
        }
        __syncthreads();
        short8 af[4], bfr[4];
#pragma unroll
        for (int i = 0; i < 4; i++)
            af[i] = *(const short8*)&As[(wr * 64 + i * 16 + lrow) * 32 + quad * 8];
#pragma unroll
        for (int j = 0; j < 4; j++)
            bfr[j] = *(const short8*)&Bs[(wc * 64 + j * 16 + lrow) * 32 + quad * 8];
#pragma unroll
        for (int i = 0; i < 4; i++)
#pragma unroll
            for (int j = 0; j < 4; j++)
                acc[i][j] = __builtin_amdgcn_mfma_f32_16x16x32_bf16(af[i], bfr[j], acc[i][j], 0, 0, 0);
    }

#pragma unroll
    for (int i = 0; i < 4; i++) {
#pragma unroll
        for (int j = 0; j < 4; j++) {
            int col = bn + wc * 64 + j * 16 + lrow;
            float bv = bias ? bias[col] : 0.f;
#pragma unroll
            for (int r = 0; r < 4; r++) {
                size_t row = (size_t)(bm + wr * 64 + i * 16 + quad * 4 + r);
                float v = acc[i][j][r] + bv;
                if (out_bf16) {
                    ((__hip_bfloat16*)C)[row * ldc + col] = __float2bfloat16(v);
                } else {
                    float* cp = (float*)C + row * ldc + col;
                    if (accum) *cp += v;
                    else       *cp = v;
                }
            }
        }
    }
}

static inline void mgemm(hipStream_t st, const __hip_bfloat16* A, int lda,
                         const __hip_bfloat16* Bt, int ldb, const float* bias,
                         void* C, int ldc, int M, int Ncols, int K,
                         int out_bf16, int accum)
{
    dim3 grid(M / 128, Ncols / 128);
    mgemm_kernel<<<grid, 256, 0, st>>>(A, lda, Bt, ldb, bias, C, ldc, K, out_bf16, accum);
}

// ================= small fp32 GEMM (stage-3 MLP only) =================
__global__ __launch_bounds__(256) void gemm_kernel(
    const float* __restrict__ A, int lda,
    const float* __restrict__ B, int ldb,
    const float* __restrict__ bias,
    float* __restrict__ C, int ldc,
    int K, int act)
{
    __shared__ float As[32][68];
    __shared__ float Bs[32][68];
    const int tid = threadIdx.x;
    const int bm = blockIdx.x * 64;
    const int bn = blockIdx.y * 64;
    const int tm = (tid & 15) * 4;
    const int tn = (tid >> 4) * 4;
    float acc[4][4] = {};

    for (int k0 = 0; k0 < K; k0 += 32) {
#pragma unroll
        for (int p = 0; p < 2; p++) {
            int lin = p * 256 + tid;
            int ar = lin >> 3;
            int ac = (lin & 7) << 2;
            float4 av = *(const float4*)(A + (size_t)(bm + ar) * lda + (k0 + ac));
            As[ac + 0][ar] = av.x;
            As[ac + 1][ar] = av.y;
            As[ac + 2][ar] = av.z;
            As[ac + 3][ar] = av.w;
            int br = lin >> 4;
            int bc = (lin & 15) << 2;
            *(float4*)&Bs[br][bc] = *(const float4*)(B + (size_t)(k0 + br) * ldb + (bn + bc));
        }
        __syncthreads();
#pragma unroll
        for (int k = 0; k < 32; k++) {
            float4 a4 = *(const float4*)&As[k][tm];
            float4 b4 = *(const float4*)&Bs[k][tn];
            float av[4] = {a4.x, a4.y, a4.z, a4.w};
            float bv[4] = {b4.x, b4.y, b4.z, b4.w};
#pragma unroll
            for (int i = 0; i < 4; i++)
#pragma unroll
                for (int j = 0; j < 4; j++)
                    acc[i][j] += av[i] * bv[j];
        }
        __syncthreads();
    }
#pragma unroll
    for (int i = 0; i < 4; i++) {
        size_t row = (size_t)(bm + tm + i);
#pragma unroll
        for (int j = 0; j < 4; j++) {
            int col = bn + tn + j;
            float val = acc[i][j] + (bias ? bias[col] : 0.f);
            if (act == 1) val = fmaxf(val, 0.f);
            C[row * ldc + col] = val;
        }
    }
}

// ================= weight prep =================
// Fragment-ordered message weights:
// Bfrag[((et*4+ch)*4 + wave)*2 + j][lane][m] = W[et][k][c], k=ch*32+quad*8+m, c=wave*32+j*16+lrow
__global__ void prep_bfrag_kernel(const float* __restrict__ W, __hip_bfloat16* __restrict__ Bf,
                                  int net)
{
    int idx = blockIdx.x * blockDim.x + threadIdx.x;   // net*16384
    int m = idx & 7;
    int lane = (idx >> 3) & 63;
    int rest = idx >> 9;
    int j = rest & 1; rest >>= 1;
    int wv = rest & 3; rest >>= 2;
    int ch = rest & 3;
    int et = rest >> 2;
    int quad = lane >> 4, lrow = lane & 15;
    int k = ch * 32 + quad * 8 + m;
    int c = wv * 32 + j * 16 + lrow;
    Bf[idx] = __float2bfloat16(W[et * 16384 + k * 128 + c]);
}

// GRU fused weights: Bt[512 cols][288 rows]; rows 0..127 a-part, 128..255 h-part,
// 256..256+net: (b @ wih)-rows for the cnt columns (exact edge-bias folding).
__global__ void prep_gru_kernel(const float* __restrict__ wih, const float* __restrict__ whh,
                                const float* __restrict__ bih, const float* __restrict__ bhh,
                                const float* __restrict__ b, int net,
                                __hip_bfloat16* __restrict__ Bt, float* __restrict__ bias)
{
    int idx = blockIdx.x * blockDim.x + threadIdx.x;   // 512*288
    int n = idx / 288;
    int k = idx - n * 288;
    float val = 0.f;
    if (k < 128) {                                     // a-part
        val = (n < 384) ? wih[k * 384 + n] : 0.f;
    } else if (k < 256) {                              // h-part
        int kk = k - 128;
        if (n < 256)      val = whh[kk * 384 + n];
        else if (n >= 384) val = whh[kk * 384 + (n - 128)];
    } else {                                           // cnt columns -> b @ wih
        int j = k - 256;
        if (j < net && n < 384) {
            float s = 0.f;
            for (int kk = 0; kk < 128; kk++) s += b[j * 128 + kk] * wih[kk * 384 + n];
            val = s;
        }
    }
    Bt[idx] = __float2bfloat16(val);
    if (k == 0) bias[n] = (n < 256) ? bih[n] + bhh[n] : (n < 384 ? bih[n] : bhh[n - 128]);
}

__global__ void prep_ro1_kernel(const float* __restrict__ iw, const float* __restrict__ jw,
                                const float* __restrict__ ib, const float* __restrict__ jb,
                                __hip_bfloat16* __restrict__ Bt, float* __restrict__ bias)
{
    int idx = blockIdx.x * blockDim.x + threadIdx.x;   // 32768
    int n = idx >> 7;
    int k = idx & 127;
    float val = (n < 128) ? iw[k * 128 + n] : jw[k * 128 + (n - 128)];
    Bt[idx] = __float2bfloat16(val);
    if (k == 0) bias[n] = (n < 128) ? ib[n] : jb[n - 128];
}

__global__ void prep_ro2_kernel(const float* __restrict__ iw, __hip_bfloat16* __restrict__ Bt,
                                int Fin)
{
    int idx = blockIdx.x * blockDim.x + threadIdx.x;   // 128*Fin
    int n = idx / Fin;
    int k = idx - n * Fin;
    Bt[idx] = __float2bfloat16(iw[(128 + k) * 128 + n]);
}

__global__ void f2b_kernel(const float* __restrict__ f, __hip_bfloat16* __restrict__ b)
{
    int idx = blockIdx.x * blockDim.x + threadIdx.x;
    b[idx] = __float2bfloat16(f[idx]);
}

// ================= CSR build (merged: key = base + dst*net + et) =================
__global__ void histk_kernel(const int* __restrict__ dst, const int* __restrict__ et,
                             int E, int net, int base, int* __restrict__ counts)
{
    int e = blockIdx.x * blockDim.x + threadIdx.x;
    if (e < E) atomicAdd(&counts[base + dst[e] * net + et[e]], 1);
}

__global__ void scan1_kernel(const int* __restrict__ counts, int* __restrict__ local_ex,
                             int* __restrict__ partial)
{
    __shared__ int s[256];
    int t = threadIdx.x;
    int i = blockIdx.x * 256 + t;
    int v = counts[i];
    s[t] = v;
    __syncthreads();
    for (int off = 1; off < 256; off <<= 1) {
        int x = 0;
        if (t >= off) x = s[t - off];
        __syncthreads();
        if (t >= off) s[t] += x;
        __syncthreads();
    }
    local_ex[i] = s[t] - v;
    if (t == 255) partial[blockIdx.x] = s[255];
}

// level-2 scan over up to 2816 partials (11 serial per thread)
__global__ void scan2b_kernel(int* __restrict__ partial, int nb, int* __restrict__ last, int E)
{
    __shared__ int s[256];
    int t = threadIdx.x;
    int loc[11];
    int sum = 0;
#pragma unroll
    for (int q = 0; q < 11; q++) {
        int idx = t * 11 + q;
        int v = (idx < nb) ? partial[idx] : 0;
        loc[q] = sum; sum += v;
    }
    s[t] = sum;
    __syncthreads();
    for (int off = 1; off < 256; off <<= 1) {
        int x = 0;
        if (t >= off) x = s[t - off];
        __syncthreads();
        if (t >= off) s[t] += x;
        __syncthreads();
    }
    int excl = s[t] - sum;
#pragma unroll
    for (int q = 0; q < 11; q++) {
        int idx = t * 11 + q;
        if (idx < nb) partial[idx] = excl + loc[q];
    }
    if (t == 0) *last = E;
}

__global__ void scan3_kernel(int* __restrict__ indptr, const int* __restrict__ partial)
{
    int i = blockIdx.x * 256 + threadIdx.x;
    indptr[i] += partial[blockIdx.x];
}

__global__ void copy_int_kernel(const int* __restrict__ a, int* __restrict__ b)
{
    int i = blockIdx.x * blockDim.x + threadIdx.x;
    b[i] = a[i];
}

__global__ void fillk_kernel(const int* __restrict__ src, const int* __restrict__ dst,
                             const int* __restrict__ et, int E, int net, int base,
                             int* __restrict__ cursor, int* __restrict__ elist)
{
    int e = blockIdx.x * blockDim.x + threadIdx.x;
    if (e >= E) return;
    int pos = atomicAdd(&cursor[base + dst[e] * net + et[e]], 1);
    elist[pos] = src[e];
}

// cnt columns of ah: ah[v][256+j] = bf16(deg(v, et=j)), zeros for j >= net
__global__ void cnt_kernel(const int* __restrict__ indptr, int net, ushort* __restrict__ ah)
{
    int idx = blockIdx.x * blockDim.x + threadIdx.x;   // N*32
    int v = idx >> 5;
    int j = idx & 31;
    float cv = 0.f;
    if (j < net) cv = (float)(indptr[v * net + j + 1] - indptr[v * net + j]);
    ah[(size_t)v * AH_S + 256 + j] = f2bu(cv);
}

// ================= elementwise =================
// feat (fp32 or bf16) -> h fp32 + ah h-cols bf16
__global__ void pad_kernel(const float* __restrict__ fsrc, const ushort* __restrict__ bsrc,
                           float* __restrict__ h, uint* __restrict__ ahp, int Fin)
{
    int idx = blockIdx.x * blockDim.x + threadIdx.x;   // N*32
    int v = idx >> 5;
    int c = (idx & 31) * 4;
    float4 val = make_float4(0.f, 0.f, 0.f, 0.f);
    if (bsrc) {
        uint2 u = *(const uint2*)(bsrc + (size_t)v * Fin + c);
        val.x = __uint_as_float(u.x << 16);
        val.y = __uint_as_float(u.x & 0xFFFF0000u);
        val.z = __uint_as_float(u.y << 16);
        val.w = __uint_as_float(u.y & 0xFFFF0000u);
    } else if (c < Fin) {
        val = *(const float4*)(fsrc + (size_t)v * Fin + c);
    }
    *(float4*)(h + (size_t)v * 128 + c) = val;
    uint2 pk;
    pk.x = (uint)f2bu(val.x) | ((uint)f2bu(val.y) << 16);
    pk.y = (uint)f2bu(val.z) | ((uint)f2bu(val.w) << 16);
    *(uint2*)(ahp + (size_t)v * AH_U + 64 + c / 2) = pk;
}

__global__ void gru_gate_kernel(const float* __restrict__ rzin, float* __restrict__ h,
                                uint* __restrict__ ahp)
{
    int idx = blockIdx.x * blockDim.x + threadIdx.x;   // N*32
    int v = idx >> 5;
    int c = (idx & 31) * 4;
    const float* base = rzin + (size_t)v * 512;
    float4 r4 = *(const float4*)(base + c);
    float4 z4 = *(const float4*)(base + 128 + c);
    float4 i4 = *(const float4*)(base + 256 + c);
    float4 n4 = *(const float4*)(base + 384 + c);
    float4 h4 = *(const float4*)(h + (size_t)v * 128 + c);
    float4 o;
    {
        float r = sigmoidf_(r4.x), z = sigmoidf_(z4.x);
        o.x = (1.f - z) * tanhf(i4.x + r * n4.x) + z * h4.x;
        r = sigmoidf_(r4.y); z = sigmoidf_(z4.y);
        o.y = (1.f - z) * tanhf(i4.y + r * n4.y) + z * h4.y;
        r = sigmoidf_(r4.z); z = sigmoidf_(z4.z);
        o.z = (1.f - z) * tanhf(i4.z + r * n4.z) + z * h4.z;
        r = sigmoidf_(r4.w); z = sigmoidf_(z4.w);
        o.w = (1.f - z) * tanhf(i4.w + r * n4.w) + z * h4.w;
    }
    *(float4*)(h + (size_t)v * 128 + c) = o;
    uint2 pk;
    pk.x = (uint)f2bu(o.x) | ((uint)f2bu(o.y) << 16);
    pk.y = (uint)f2bu(o.z) | ((uint)f2bu(o.w) << 16);
    *(uint2*)(ahp + (size_t)v * AH_U + 64 + c / 2) = pk;
}

// o = sigmoid(uv[:,0:128]) * uv[:,128:256]; fp32 out (opt) + bf16 out (opt)
__global__ void sigmul_kernel(const float* __restrict__ uv, float* __restrict__ o,
                              uint* __restrict__ obp)
{
    int idx = blockIdx.x * blockDim.x + threadIdx.x;   // N*32
    int v = idx >> 5;
    int c = (idx & 31) * 4;
    float4 u4 = *(const float4*)(uv + (size_t)v * 256 + c);
    float4 v4 = *(const float4*)(uv + (size_t)v * 256 + 128 + c);
    float4 r;
    r.x = sigmoidf_(u4.x) * v4.x;
    r.y = sigmoidf_(u4.y) * v4.y;
    r.z = sigmoidf_(u4.z) * v4.z;
    r.w = sigmoidf_(u4.w) * v4.w;
    if (o) *(float4*)(o + (size_t)v * 128 + c) = r;
    if (obp) {
        uint2 pk;
        pk.x = (uint)f2bu(r.x) | ((uint)f2bu(r.y) << 16);
        pk.y = (uint)f2bu(r.z) | ((uint)f2bu(r.w) << 16);
        *(uint2*)(obp + (size_t)v * 64 + c / 2) = pk;
    }
}

__global__ void pool_kernel(const float* __restrict__ r2, float* __restrict__ pooled)
{
    int s = blockIdx.x;
    int c = threadIdx.x;
    const float* base = r2 + (size_t)(2 * s) * PER * 128;
    float acc = 0.f;
    for (int i = 0; i < PER; i++) acc += base[(size_t)i * 128 + c];
    pooled[s * 128 + c] = acc;
}

__global__ void out_kernel(const float* __restrict__ x2, const float* __restrict__ wo,
                           const float* __restrict__ bo, float* __restrict__ out)
{
    int row = blockIdx.x;
    int t = threadIdx.x;
    float s = x2[row * 128 + t] * wo[t] + x2[row * 128 + 64 + t] * wo[64 + t];
#pragma unroll
    for (int off = 32; off; off >>= 1) s += __shfl_down(s, off);
    if (t == 0) out[row] = s + bo[0];
}

struct GGParams {
    const float *W, *b, *wih, *whh, *bih, *bhh, *iw, *ib, *jw, *jb;
};

struct WsPtrs {
    float* h;                 // [N,128] fp32 GRU state
    __hip_bfloat16* ah;       // [N,288] bf16: [a | h | cnt]
    float* G;                 // 4*n128 floats: rzin / uv ; rout2 at +2*n128
    __hip_bfloat16* r1b;      // stage-1 readout bf16 [N,128]
    __hip_bfloat16* featb;    // feat bf16 [N,64]
    __hip_bfloat16 *bfragB, *gruB, *ro1B, *ro2B;
    float *gruBias, *ro1Bias;
    int *indptr, *cursor, *partial, *elist;
    float *pooled, *x1, *x2;
};

template<int NET>
static void run_stage(hipStream_t st, const float* featF, const __hip_bfloat16* featB, int Fin,
                      const GGParams& p, const WsPtrs& w, const int* indptr_slice,
                      float* rout, __hip_bfloat16* rout_b)
{
    const int N = N_NODES;
    float* rzin = w.G;
    float* uv   = w.G;
    uint* ahp = (uint*)w.ah;

    // weight prep
    prep_bfrag_kernel<<<(NET * 16384) / 256, 256, 0, st>>>(p.W, w.bfragB, NET);
    prep_gru_kernel<<<(512 * 288) / 256, 256, 0, st>>>(p.wih, p.whh, p.bih, p.bhh, p.b, NET,
                                                       w.gruB, w.gruBias);
    prep_ro1_kernel<<<32768 / 256, 256, 0, st>>>(p.iw, p.jw, p.ib, p.jb, w.ro1B, w.ro1Bias);
    prep_ro2_kernel<<<(128 * Fin) / 256, 256, 0, st>>>(p.iw, w.ro2B, Fin);

    cnt_kernel<<<(N * 32) / 256, 256, 0, st>>>(indptr_slice, NET, (ushort*)w.ah);
    pad_kernel<<<(N * 32) / 256, 256, 0, st>>>(featF, (const ushort*)featB, w.h, ahp, Fin);

    for (int step = 0; step < 2; step++) {
        msg_kernel<NET><<<N / 64, 256, 0, st>>>(ahp, indptr_slice, w.elist, (ushort*)w.bfragB,
                                                (ushort*)w.ah);
        // rz|in|hn = [a, h, cnt] @ gruB + bias   (cnt cols apply per-edge biases exactly)
        mgemm(st, w.ah, AH_S, w.gruB, 288, w.gruBias, rzin, 512, N, 512, 288, 0, 0);
        gru_gate_kernel<<<(N * 32) / 256, 256, 0, st>>>(rzin, w.h, ahp);
    }

    // readout: uv = [ h@iwh + feat@iwf + ib | h@jw + jb ]
    mgemm(st, w.ah + 128, AH_S, w.ro1B, 128, w.ro1Bias, uv, 256, N, 256, 128, 0, 0);
    const __hip_bfloat16* fB = featB ? featB : w.featb;   // stage1 uses featb
    mgemm(st, fB, Fin, w.ro2B, Fin, nullptr, uv, 256, N, 128, Fin, 0, 1);
    sigmul_kernel<<<(N * 32) / 256, 256, 0, st>>>(uv, rout, (uint*)rout_b);
}

extern "C" void kernel_launch(void* const* d_in, const int* in_sizes, int n_in,
                              void* d_out, int out_size, void* d_ws, size_t ws_size,
                              hipStream_t stream)
{
    const float* feat    = (const float*)d_in[0];
    const int*   bi_src  = (const int*)d_in[1];
    const int*   bi_dst  = (const int*)d_in[2];
    const int*   bi_et   = (const int*)d_in[3];
    const int*   knn_src = (const int*)d_in[4];
    const int*   knn_dst = (const int*)d_in[5];
    const int*   knn_et  = (const int*)d_in[6];

    GGParams s1 { (const float*)d_in[8],  (const float*)d_in[9],  (const float*)d_in[10],
                  (const float*)d_in[11], (const float*)d_in[12], (const float*)d_in[13],
                  (const float*)d_in[14], (const float*)d_in[15], (const float*)d_in[16],
                  (const float*)d_in[17] };
    GGParams s2 { (const float*)d_in[18], (const float*)d_in[19], (const float*)d_in[20],
                  (const float*)d_in[21], (const float*)d_in[22], (const float*)d_in[23],
                  (const float*)d_in[24], (const float*)d_in[25], (const float*)d_in[26],
                  (const float*)d_in[27] };
    const float* w0 = (const float*)d_in[28];
    const float* b0 = (const float*)d_in[29];
    const float* w1 = (const float*)d_in[30];
    const float* b1 = (const float*)d_in[31];
    const float* wo = (const float*)d_in[32];
    const float* bo = (const float*)d_in[33];

    const int N = N_NODES;
    const size_t n128 = (size_t)N * 128;

    float* ws = (float*)d_ws;
    WsPtrs w;
    size_t off = 0;
    w.h      = ws + off;                       off += n128;
    w.ah     = (__hip_bfloat16*)(ws + off);    off += (size_t)N * 144;  // N*288 bf16
    w.G      = ws + off;                       off += 4 * n128;
    w.r1b    = (__hip_bfloat16*)(ws + off);    off += n128 / 2;
    w.featb  = (__hip_bfloat16*)(ws + off);    off += n128 / 4;
    w.bfragB = (__hip_bfloat16*)(ws + off);    off += 9 * 16384 / 2;
    w.gruB   = (__hip_bfloat16*)(ws + off);    off += 512 * 288 / 2;
    w.ro1B   = (__hip_bfloat16*)(ws + off);    off += 32768 / 2;
    w.ro2B   = (__hip_bfloat16*)(ws + off);    off += 16384 / 2;
    w.gruBias = ws + off;                      off += 512;
    w.ro1Bias = ws + off;                      off += 256;
    w.indptr  = (int*)(ws + off);              off += KN_TOT + 8;
    w.cursor  = (int*)(ws + off);              off += KN_TOT;
    w.partial = (int*)(ws + off);              off += 4096;
    w.elist   = (int*)(ws + off);              off += E_TOT;
    w.pooled  = ws + off;                      off += 64 * 128;
    w.x1      = ws + off;                      off += 64 * 256;
    w.x2      = ws + off;                      off += 64 * 128;

    // ---- merged CSR build for both graphs (concatenated keyspace) ----
    hipMemsetAsync(w.cursor, 0, KN_TOT * sizeof(int), stream);
    histk_kernel<<<(E_BI + 255) / 256, 256, 0, stream>>>(bi_dst, bi_et, E_BI, 5, 0, w.cursor);
    histk_kernel<<<(E_KNN + 255) / 256, 256, 0, stream>>>(knn_dst, knn_et, E_KNN, 9, KN_BI, w.cursor);
    scan1_kernel<<<KN_TOT / 256, 256, 0, stream>>>(w.cursor, w.indptr, w.partial);
    scan2b_kernel<<<1, 256, 0, stream>>>(w.partial, KN_TOT / 256, w.indptr + KN_TOT, E_TOT);
    scan3_kernel<<<KN_TOT / 256, 256, 0, stream>>>(w.indptr, w.partial);
    copy_int_kernel<<<KN_TOT / 256, 256, 0, stream>>>(w.indptr, w.cursor);
    fillk_kernel<<<(E_BI + 255) / 256, 256, 0, stream>>>(bi_src, bi_dst, bi_et, E_BI, 5, 0,
                                                         w.cursor, w.elist);
    fillk_kernel<<<(E_KNN + 255) / 256, 256, 0, stream>>>(knn_src, knn_dst, knn_et, E_KNN, 9, KN_BI,
                                                          w.cursor, w.elist);

    f2b_kernel<<<(N * 64) / 256, 256, 0, stream>>>(feat, w.featb);

    // Stage 1: bond graph (5 etypes), Fin=64, fp32 feat input
    run_stage<5>(stream, feat, nullptr, 64, s1, w, w.indptr, nullptr, w.r1b);
    // Stage 2: knn graph (9 etypes), feat = stage-1 readout (bf16)
    float* rout2 = w.G + 2 * n128;
    run_stage<9>(stream, nullptr, w.r1b, 128, s2, w, w.indptr + KN_BI, rout2, nullptr);

    // Stage 3: ligand pooling + MLP
    pool_kernel<<<64, 128, 0, stream>>>(rout2, w.pooled);
    {
        dim3 g1(1, 4);
        gemm_kernel<<<g1, 256, 0, stream>>>(w.pooled, 128, w0, 256, b0, w.x1, 256, 128, 1);
        dim3 g2(1, 2);
        gemm_kernel<<<g2, 256, 0, stream>>>(w.x1, 256, w1, 128, b1, w.x2, 128, 256, 1);
    }
    out_kernel<<<64, 64, 0, stream>>>(w.x2, wo, bo, (float*)d_out);
}

// Round 7
// 878.692 us; speedup vs baseline: 5.2543x; 1.0610x over previous
//
#include <hip/hip_runtime.h>
#include <hip/hip_bf16.h>

#define N_NODES 50176
#define PER 392
#define E_BI (N_NODES * 4)      // 200704
#define E_KNN (N_NODES * 16)    // 802816
#define E_TOT (E_BI + E_KNN)    // 1003520
#define KN_BI (N_NODES * 5)     // 250880
#define KN_TOT (N_NODES * 14)   // 702464
#define AH_S 288                // ah row stride (shorts): [a(128) | h(128) | cnt(32)]
#define AH_U 144

typedef __attribute__((ext_vector_type(8))) short short8;
typedef __attribute__((ext_vector_type(4))) float float4v;
typedef unsigned int uint;
typedef unsigned short ushort;

__device__ __forceinline__ float sigmoidf_(float x) { return 1.f / (1.f + __expf(-x)); }
__device__ __forceinline__ ushort f2bu(float x) {
    __hip_bfloat16 t = __float2bfloat16(x);
    return *reinterpret_cast<ushort*>(&t);
}
__device__ __forceinline__ float blo(uint u) { return __uint_as_float(u << 16); }
__device__ __forceinline__ float bhi(uint u) { return __uint_as_float(u & 0xFFFF0000u); }

// ================= fused aggregate + per-etype transform (v4) =================
// Block = 32 node rows, 256 threads: 8 threads/row (16 ch each). Gather from compact
// aligned hb[N,128]b16. 4 waves: (row-half, col-half) tiles of 16x64. B fragment-ordered.
template<int NET>
__global__ __launch_bounds__(256) void msg_kernel(
    const uint* __restrict__ hb,           // [N][64] uints (h bf16 packed)
    const int* __restrict__ indptr,        // [N*NET+1] slice (absolute into elist)
    const int* __restrict__ elist,
    const ushort* __restrict__ Bfrag,      // fragment-ordered weights
    ushort* __restrict__ aout)             // ah base; write cols 0..127, stride AH_S
{
    __shared__ ushort As[4][32][40];       // 10.25 KB, chunk-major, 80B rows
    const int tid = threadIdx.x;
    const int bm = blockIdx.x * 32;
    const int wave = tid >> 6, lane = tid & 63;
    const int quad = lane >> 4, lrow = lane & 15;
    const int wr = wave & 1, wc = wave >> 1;
    const int r = tid >> 3;                // node row 0..31
    const int oct = tid & 7;               // 16-ch group
    const int v = bm + r;

    uint* AsU = (uint*)As;                 // [ch][r][20] uints

    float4v acc[4] = {};

    for (int et = 0; et < NET; et++) {
        const int beg = indptr[v * NET + et], end = indptr[v * NET + et + 1];
        float av[16];
#pragma unroll
        for (int i = 0; i < 16; i++) av[i] = 0.f;

        for (int j = beg; j < end; j++) {
            int src = elist[j];
            const uint4* hp = (const uint4*)(hb + (size_t)src * 64 + oct * 8);
            uint4 u0 = hp[0];
            uint4 u1 = hp[1];
            av[0] += blo(u0.x); av[1] += bhi(u0.x);
            av[2] += blo(u0.y); av[3] += bhi(u0.y);
            av[4] += blo(u0.z); av[5] += bhi(u0.z);
            av[6] += blo(u0.w); av[7] += bhi(u0.w);
            av[8]  += blo(u1.x); av[9]  += bhi(u1.x);
            av[10] += blo(u1.y); av[11] += bhi(u1.y);
            av[12] += blo(u1.z); av[13] += bhi(u1.z);
            av[14] += blo(u1.w); av[15] += bhi(u1.w);
        }

        __syncthreads();                   // previous etype's As reads complete
        {
            int base = ((oct >> 1) * 32 + r) * 20 + (oct & 1) * 8;
#pragma unroll
            for (int u = 0; u < 8; u++)
                AsU[base + u] = (uint)f2bu(av[2 * u]) | ((uint)f2bu(av[2 * u + 1]) << 16);
        }
        __syncthreads();

#pragma unroll
        for (int ch = 0; ch < 4; ch++) {
            short8 af = *(const short8*)&As[ch][wr * 16 + lrow][quad * 8];
            const ushort* bp = Bfrag + ((size_t)(((et * 4 + ch) * 2 + wc) * 4) << 9) + lane * 8;
#pragma unroll
            for (int j = 0; j < 4; j++) {
                short8 bfr = *(const short8*)(bp + j * 512);
                acc[j] = __builtin_amdgcn_mfma_f32_16x16x32_bf16(af, bfr, acc[j], 0, 0, 0);
            }
        }
    }

    // epilogue: a -> ah cols 0..127
#pragma unroll
    for (int j = 0; j < 4; j++) {
        int col = wc * 64 + j * 16 + lrow;
#pragma unroll
        for (int rr = 0; rr < 4; rr++) {
            size_t row = (size_t)(bm + wr * 16 + quad * 4 + rr);
            aout[row * AH_S + col] = f2bu(acc[j][rr]);
        }
    }
}

// ================= bf16 MFMA GEMM (GRU / readout) =================
__global__ __launch_bounds__(256) void mgemm_kernel(
    const __hip_bfloat16* __restrict__ A, int lda,
    const __hip_bfloat16* __restrict__ Bt, int ldb,
    const float* __restrict__ bias,
    void* __restrict__ C, int ldc, int K,
    int out_bf16, int accum)
{
    __shared__ short As[128 * 32];
    __shared__ short Bs[128 * 32];
    const int tid = threadIdx.x;
    const int bm = blockIdx.x * 128;
    const int bn = blockIdx.y * 128;
    const int wave = tid >> 6, lane = tid & 63;
    const int quad = lane >> 4, lrow = lane & 15;
    const int wr = wave & 1, wc = wave >> 1;

    const short* Ap = (const short*)A;
    const short* Bp = (const short*)Bt;

    float4v acc[4][4] = {};

    for (int k0 = 0; k0 < K; k0 += 32) {
        __syncthreads();
#pragma unroll
        for (int p = 0; p < 2; p++) {
            int lin = p * 256 + tid;
            int r = lin >> 2;
            int kc = (lin & 3) * 8;
            *(short8*)&As[r * 32 + kc] = *(const short8*)(Ap + (size_t)(bm + r) * lda + k0 + kc);
            *(short8*)&Bs[r * 32 + kc] = *(const short8*)(Bp + (size_t)(bn + r) * ldb + k0 + kc);
        }
        __syncthreads();
        short8 af[4], bfr[4];
#pragma unroll
        for (int i = 0; i < 4; i++)
            af[i] = *(const short8*)&As[(wr * 64 + i * 16 + lrow) * 32 + quad * 8];
#pragma unroll
        for (int j = 0; j < 4; j++)
            bfr[j] = *(const short8*)&Bs[(wc * 64 + j * 16 + lrow) * 32 + quad * 8];
#pragma unroll
        for (int i = 0; i < 4; i++)
#pragma unroll
            for (int j = 0; j < 4; j++)
                acc[i][j] = __builtin_amdgcn_mfma_f32_16x16x32_bf16(af[i], bfr[j], acc[i][j], 0, 0, 0);
    }

#pragma unroll
    for (int i = 0; i < 4; i++) {
#pragma unroll
        for (int j = 0; j < 4; j++) {
            int col = bn + wc * 64 + j * 16 + lrow;
            float bv = bias ? bias[col] : 0.f;
#pragma unroll
            for (int r = 0; r < 4; r++) {
                size_t row = (size_t)(bm + wr * 64 + i * 16 + quad * 4 + r);
                float v = acc[i][j][r] + bv;
                if (out_bf16) {
                    ((__hip_bfloat16*)C)[row * ldc + col] = __float2bfloat16(v);
                } else {
                    float* cp = (float*)C + row * ldc + col;
                    if (accum) *cp += v;
                    else       *cp = v;
                }
            }
        }
    }
}

static inline void mgemm(hipStream_t st, const __hip_bfloat16* A, int lda,
                         const __hip_bfloat16* Bt, int ldb, const float* bias,
                         void* C, int ldc, int M, int Ncols, int K,
                         int out_bf16, int accum)
{
    dim3 grid(M / 128, Ncols / 128);
    mgemm_kernel<<<grid, 256, 0, st>>>(A, lda, Bt, ldb, bias, C, ldc, K, out_bf16, accum);
}

// ================= small fp32 GEMM (stage-3 MLP only) =================
__global__ __launch_bounds__(256) void gemm_kernel(
    const float* __restrict__ A, int lda,
    const float* __restrict__ B, int ldb,
    const float* __restrict__ bias,
    float* __restrict__ C, int ldc,
    int K, int act)
{
    __shared__ float As[32][68];
    __shared__ float Bs[32][68];
    const int tid = threadIdx.x;
    const int bm = blockIdx.x * 64;
    const int bn = blockIdx.y * 64;
    const int tm = (tid & 15) * 4;
    const int tn = (tid >> 4) * 4;
    float acc[4][4] = {};

    for (int k0 = 0; k0 < K; k0 += 32) {
#pragma unroll
        for (int p = 0; p < 2; p++) {
            int lin = p * 256 + tid;
            int ar = lin >> 3;
            int ac = (lin & 7) << 2;
            float4 av = *(const float4*)(A + (size_t)(bm + ar) * lda + (k0 + ac));
            As[ac + 0][ar] = av.x;
            As[ac + 1][ar] = av.y;
            As[ac + 2][ar] = av.z;
            As[ac + 3][ar] = av.w;
            int br = lin >> 4;
            int bc = (lin & 15) << 2;
            *(float4*)&Bs[br][bc] = *(const float4*)(B + (size_t)(k0 + br) * ldb + (bn + bc));
        }
        __syncthreads();
#pragma unroll
        for (int k = 0; k < 32; k++) {
            float4 a4 = *(const float4*)&As[k][tm];
            float4 b4 = *(const float4*)&Bs[k][tn];
            float av[4] = {a4.x, a4.y, a4.z, a4.w};
            float bv[4] = {b4.x, b4.y, b4.z, b4.w};
#pragma unroll
            for (int i = 0; i < 4; i++)
#pragma unroll
                for (int j = 0; j < 4; j++)
                    acc[i][j] += av[i] * bv[j];
        }
        __syncthreads();
    }
#pragma unroll
    for (int i = 0; i < 4; i++) {
        size_t row = (size_t)(bm + tm + i);
#pragma unroll
        for (int j = 0; j < 4; j++) {
            int col = bn + tn + j;
            float val = acc[i][j] + (bias ? bias[col] : 0.f);
            if (act == 1) val = fmaxf(val, 0.f);
            C[row * ldc + col] = val;
        }
    }
}

// ================= weight prep =================
// Bfrag[(((et*4+ch)*2+wc)*4 + j)][lane][m] = W[et][k][c], k=ch*32+quad*8+m, c=wc*64+j*16+lrow
__global__ void prep_bfrag_kernel(const float* __restrict__ W, __hip_bfloat16* __restrict__ Bf,
                                  int net)
{
    int idx = blockIdx.x * blockDim.x + threadIdx.x;   // net*16384
    int m = idx & 7;
    int lane = (idx >> 3) & 63;
    int f = idx >> 9;
    int j = f & 3; f >>= 2;
    int wc = f & 1; f >>= 1;
    int ch = f & 3;
    int et = f >> 2;
    int quad = lane >> 4, lrow = lane & 15;
    int k = ch * 32 + quad * 8 + m;
    int c = wc * 64 + j * 16 + lrow;
    Bf[idx] = __float2bfloat16(W[et * 16384 + k * 128 + c]);
}

// GRU fused weights: Bt[512 cols][288 rows]; rows 0..127 a, 128..255 h, 256+: b@wih (cnt cols)
__global__ void prep_gru_kernel(const float* __restrict__ wih, const float* __restrict__ whh,
                                const float* __restrict__ bih, const float* __restrict__ bhh,
                                const float* __restrict__ b, int net,
                                __hip_bfloat16* __restrict__ Bt, float* __restrict__ bias)
{
    int idx = blockIdx.x * blockDim.x + threadIdx.x;   // 512*288
    int n = idx / 288;
    int k = idx - n * 288;
    float val = 0.f;
    if (k < 128) {
        val = (n < 384) ? wih[k * 384 + n] : 0.f;
    } else if (k < 256) {
        int kk = k - 128;
        if (n < 256)       val = whh[kk * 384 + n];
        else if (n >= 384) val = whh[kk * 384 + (n - 128)];
    } else {
        int j = k - 256;
        if (j < net && n < 384) {
            float s = 0.f;
            for (int kk = 0; kk < 128; kk++) s += b[j * 128 + kk] * wih[kk * 384 + n];
            val = s;
        }
    }
    Bt[idx] = __float2bfloat16(val);
    if (k == 0) bias[n] = (n < 256) ? bih[n] + bhh[n] : (n < 384 ? bih[n] : bhh[n - 128]);
}

__global__ void prep_ro1_kernel(const float* __restrict__ iw, const float* __restrict__ jw,
                                const float* __restrict__ ib, const float* __restrict__ jb,
                                __hip_bfloat16* __restrict__ Bt, float* __restrict__ bias)
{
    int idx = blockIdx.x * blockDim.x + threadIdx.x;   // 32768
    int n = idx >> 7;
    int k = idx & 127;
    float val = (n < 128) ? iw[k * 128 + n] : jw[k * 128 + (n - 128)];
    Bt[idx] = __float2bfloat16(val);
    if (k == 0) bias[n] = (n < 128) ? ib[n] : jb[n - 128];
}

__global__ void prep_ro2_kernel(const float* __restrict__ iw, __hip_bfloat16* __restrict__ Bt,
                                int Fin)
{
    int idx = blockIdx.x * blockDim.x + threadIdx.x;   // 128*Fin
    int n = idx / Fin;
    int k = idx - n * Fin;
    Bt[idx] = __float2bfloat16(iw[(128 + k) * 128 + n]);
}

__global__ void f2b_kernel(const float* __restrict__ f, __hip_bfloat16* __restrict__ b)
{
    int idx = blockIdx.x * blockDim.x + threadIdx.x;
    b[idx] = __float2bfloat16(f[idx]);
}

// ================= merged CSR build (both graphs, concatenated keyspace) =================
__global__ void hist2_kernel(const int* __restrict__ bd, const int* __restrict__ be,
                             const int* __restrict__ kd, const int* __restrict__ ke,
                             int* __restrict__ counts)
{
    int e = blockIdx.x * blockDim.x + threadIdx.x;
    if (e >= E_TOT) return;
    if (e < E_BI) atomicAdd(&counts[bd[e] * 5 + be[e]], 1);
    else { int i = e - E_BI; atomicAdd(&counts[KN_BI + kd[i] * 9 + ke[i]], 1); }
}

__global__ void scan1_kernel(const int* __restrict__ counts, int* __restrict__ local_ex,
                             int* __restrict__ partial)
{
    __shared__ int s[256];
    int t = threadIdx.x;
    int i = blockIdx.x * 256 + t;
    int v = counts[i];
    s[t] = v;
    __syncthreads();
    for (int off = 1; off < 256; off <<= 1) {
        int x = 0;
        if (t >= off) x = s[t - off];
        __syncthreads();
        if (t >= off) s[t] += x;
        __syncthreads();
    }
    local_ex[i] = s[t] - v;
    if (t == 255) partial[blockIdx.x] = s[255];
}

__global__ void scan2b_kernel(int* __restrict__ partial, int nb, int* __restrict__ last, int E)
{
    __shared__ int s[256];
    int t = threadIdx.x;
    int loc[11];
    int sum = 0;
#pragma unroll
    for (int q = 0; q < 11; q++) {
        int idx = t * 11 + q;
        int v = (idx < nb) ? partial[idx] : 0;
        loc[q] = sum; sum += v;
    }
    s[t] = sum;
    __syncthreads();
    for (int off = 1; off < 256; off <<= 1) {
        int x = 0;
        if (t >= off) x = s[t - off];
        __syncthreads();
        if (t >= off) s[t] += x;
        __syncthreads();
    }
    int excl = s[t] - sum;
#pragma unroll
    for (int q = 0; q < 11; q++) {
        int idx = t * 11 + q;
        if (idx < nb) partial[idx] = excl + loc[q];
    }
    if (t == 0) *last = E;
}

// add block offsets AND copy to cursor in one pass
__global__ void scan3c_kernel(int* __restrict__ indptr, const int* __restrict__ partial,
                              int* __restrict__ cursor)
{
    int i = blockIdx.x * 256 + threadIdx.x;
    int v = indptr[i] + partial[blockIdx.x];
    indptr[i] = v;
    cursor[i] = v;
}

__global__ void fill2_kernel(const int* __restrict__ bs, const int* __restrict__ bd,
                             const int* __restrict__ be,
                             const int* __restrict__ ks, const int* __restrict__ kd,
                             const int* __restrict__ ke,
                             int* __restrict__ cursor, int* __restrict__ elist)
{
    int e = blockIdx.x * blockDim.x + threadIdx.x;
    if (e >= E_TOT) return;
    if (e < E_BI) {
        int pos = atomicAdd(&cursor[bd[e] * 5 + be[e]], 1);
        elist[pos] = bs[e];
    } else {
        int i = e - E_BI;
        int pos = atomicAdd(&cursor[KN_BI + kd[i] * 9 + ke[i]], 1);
        elist[pos] = ks[i];
    }
}

// cnt columns of ah
__global__ void cnt_kernel(const int* __restrict__ indptr, int net, ushort* __restrict__ ah)
{
    int idx = blockIdx.x * blockDim.x + threadIdx.x;   // N*32
    int v = idx >> 5;
    int j = idx & 31;
    float cv = 0.f;
    if (j < net) cv = (float)(indptr[v * net + j + 1] - indptr[v * net + j]);
    ah[(size_t)v * AH_S + 256 + j] = f2bu(cv);
}

// ================= elementwise =================
// feat (fp32 or bf16) -> h fp32 + ah h-cols bf16 + hb compact bf16
__global__ void pad_kernel(const float* __restrict__ fsrc, const ushort* __restrict__ bsrc,
                           float* __restrict__ h, uint* __restrict__ ahp,
                           uint* __restrict__ hb, int Fin)
{
    int idx = blockIdx.x * blockDim.x + threadIdx.x;   // N*32
    int v = idx >> 5;
    int c = (idx & 31) * 4;
    float4 val = make_float4(0.f, 0.f, 0.f, 0.f);
    if (bsrc) {
        uint2 u = *(const uint2*)(bsrc + (size_t)v * Fin + c);
        val.x = blo(u.x); val.y = bhi(u.x);
        val.z = blo(u.y); val.w = bhi(u.y);
    } else if (c < Fin) {
        val = *(const float4*)(fsrc + (size_t)v * Fin + c);
    }
    *(float4*)(h + (size_t)v * 128 + c) = val;
    uint2 pk;
    pk.x = (uint)f2bu(val.x) | ((uint)f2bu(val.y) << 16);
    pk.y = (uint)f2bu(val.z) | ((uint)f2bu(val.w) << 16);
    *(uint2*)(ahp + (size_t)v * AH_U + 64 + c / 2) = pk;
    *(uint2*)(hb + (size_t)v * 64 + c / 2) = pk;
}

// GRU gate from bf16 rzin[N,512]: h = (1-z)*tanh(in + r*hn) + z*h
__global__ void gru_gate_kernel(const ushort* __restrict__ rzin, float* __restrict__ h,
                                uint* __restrict__ ahp, uint* __restrict__ hb)
{
    int idx = blockIdx.x * blockDim.x + threadIdx.x;   // N*32
    int v = idx >> 5;
    int c = (idx & 31) * 4;
    const ushort* base = rzin + (size_t)v * 512;
    uint2 ru = *(const uint2*)(base + c);
    uint2 zu = *(const uint2*)(base + 128 + c);
    uint2 iu = *(const uint2*)(base + 256 + c);
    uint2 nu = *(const uint2*)(base + 384 + c);
    float4 h4 = *(const float4*)(h + (size_t)v * 128 + c);
    float4 o;
    {
        float r = sigmoidf_(blo(ru.x)), z = sigmoidf_(blo(zu.x));
        o.x = (1.f - z) * tanhf(blo(iu.x) + r * blo(nu.x)) + z * h4.x;
        r = sigmoidf_(bhi(ru.x)); z = sigmoidf_(bhi(zu.x));
        o.y = (1.f - z) * tanhf(bhi(iu.x) + r * bhi(nu.x)) + z * h4.y;
        r = sigmoidf_(blo(ru.y)); z = sigmoidf_(blo(zu.y));
        o.z = (1.f - z) * tanhf(blo(iu.y) + r * blo(nu.y)) + z * h4.z;
        r = sigmoidf_(bhi(ru.y)); z = sigmoidf_(bhi(zu.y));
        o.w = (1.f - z) * tanhf(bhi(iu.y) + r * bhi(nu.y)) + z * h4.w;
    }
    *(float4*)(h + (size_t)v * 128 + c) = o;
    uint2 pk;
    pk.x = (uint)f2bu(o.x) | ((uint)f2bu(o.y) << 16);
    pk.y = (uint)f2bu(o.z) | ((uint)f2bu(o.w) << 16);
    *(uint2*)(ahp + (size_t)v * AH_U + 64 + c / 2) = pk;
    *(uint2*)(hb + (size_t)v * 64 + c / 2) = pk;
}

__global__ void sigmul_kernel(const float* __restrict__ uv, float* __restrict__ o,
                              uint* __restrict__ obp)
{
    int idx = blockIdx.x * blockDim.x + threadIdx.x;   // N*32
    int v = idx >> 5;
    int c = (idx & 31) * 4;
    float4 u4 = *(const float4*)(uv + (size_t)v * 256 + c);
    float4 v4 = *(const float4*)(uv + (size_t)v * 256 + 128 + c);
    float4 r;
    r.x = sigmoidf_(u4.x) * v4.x;
    r.y = sigmoidf_(u4.y) * v4.y;
    r.z = sigmoidf_(u4.z) * v4.z;
    r.w = sigmoidf_(u4.w) * v4.w;
    if (o) *(float4*)(o + (size_t)v * 128 + c) = r;
    if (obp) {
        uint2 pk;
        pk.x = (uint)f2bu(r.x) | ((uint)f2bu(r.y) << 16);
        pk.y = (uint)f2bu(r.z) | ((uint)f2bu(r.w) << 16);
        *(uint2*)(obp + (size_t)v * 64 + c / 2) = pk;
    }
}

__global__ void pool_kernel(const float* __restrict__ r2, float* __restrict__ pooled)
{
    int s = blockIdx.x;
    int c = threadIdx.x;
    const float* base = r2 + (size_t)(2 * s) * PER * 128;
    float acc = 0.f;
    for (int i = 0; i < PER; i++) acc += base[(size_t)i * 128 + c];
    pooled[s * 128 + c] = acc;
}

__global__ void out_kernel(const float* __restrict__ x2, const float* __restrict__ wo,
                           const float* __restrict__ bo, float* __restrict__ out)
{
    int row = blockIdx.x;
    int t = threadIdx.x;
    float s = x2[row * 128 + t] * wo[t] + x2[row * 128 + 64 + t] * wo[64 + t];
#pragma unroll
    for (int off = 32; off; off >>= 1) s += __shfl_down(s, off);
    if (t == 0) out[row] = s + bo[0];
}

struct GGParams {
    const float *W, *b, *wih, *whh, *bih, *bhh, *iw, *ib, *jw, *jb;
};

struct WsPtrs {
    float* h;
    __hip_bfloat16* ah;       // [N,288] bf16
    float* G;                 // 4*n128 floats: rzin(bf16,2u) | rout2(1u) | hb(0.5u)
    uint* hb;                 // compact h bf16 [N][64] uints
    __hip_bfloat16* r1b;
    __hip_bfloat16* featb;
    __hip_bfloat16 *bfragB, *gruB, *ro1B, *ro2B;
    float *gruBias, *ro1Bias;
    int *indptr, *cursor, *partial, *elist;
    float *pooled, *x1, *x2;
};

template<int NET>
static void run_stage(hipStream_t st, const float* featF, const __hip_bfloat16* featB, int Fin,
                      const GGParams& p, const WsPtrs& w, const int* indptr_slice,
                      float* rout, __hip_bfloat16* rout_b)
{
    const int N = N_NODES;
    ushort* rzin = (ushort*)w.G;            // [N,512] bf16
    float* uv    = w.G;                     // [N,256] fp32 (rzin dead)
    uint* ahp = (uint*)w.ah;

    prep_bfrag_kernel<<<(NET * 16384) / 256, 256, 0, st>>>(p.W, w.bfragB, NET);
    prep_gru_kernel<<<(512 * 288) / 256, 256, 0, st>>>(p.wih, p.whh, p.bih, p.bhh, p.b, NET,
                                                       w.gruB, w.gruBias);
    prep_ro1_kernel<<<32768 / 256, 256, 0, st>>>(p.iw, p.jw, p.ib, p.jb, w.ro1B, w.ro1Bias);
    prep_ro2_kernel<<<(128 * Fin) / 256, 256, 0, st>>>(p.iw, w.ro2B, Fin);

    cnt_kernel<<<(N * 32) / 256, 256, 0, st>>>(indptr_slice, NET, (ushort*)w.ah);
    pad_kernel<<<(N * 32) / 256, 256, 0, st>>>(featF, (const ushort*)featB, w.h, ahp, w.hb, Fin);

    for (int step = 0; step < 2; step++) {
        msg_kernel<NET><<<N / 32, 256, 0, st>>>(w.hb, indptr_slice, w.elist,
                                                (ushort*)w.bfragB, (ushort*)w.ah);
        // rz|in|hn = [a, h, cnt] @ gruB + bias -> bf16 rzin
        mgemm(st, w.ah, AH_S, w.gruB, 288, w.gruBias, rzin, 512, N, 512, 288, 1, 0);
        gru_gate_kernel<<<(N * 32) / 256, 256, 0, st>>>(rzin, w.h, ahp, w.hb);
    }

    // readout: uv = [ h@iwh + feat@iwf + ib | h@jw + jb ]
    mgemm(st, w.ah + 128, AH_S, w.ro1B, 128, w.ro1Bias, uv, 256, N, 256, 128, 0, 0);
    const __hip_bfloat16* fB = featB ? featB : w.featb;
    mgemm(st, fB, Fin, w.ro2B, Fin, nullptr, uv, 256, N, 128, Fin, 0, 1);
    sigmul_kernel<<<(N * 32) / 256, 256, 0, st>>>(uv, rout, (uint*)rout_b);
}

extern "C" void kernel_launch(void* const* d_in, const int* in_sizes, int n_in,
                              void* d_out, int out_size, void* d_ws, size_t ws_size,
                              hipStream_t stream)
{
    const float* feat    = (const float*)d_in[0];
    const int*   bi_src  = (const int*)d_in[1];
    const int*   bi_dst  = (const int*)d_in[2];
    const int*   bi_et   = (const int*)d_in[3];
    const int*   knn_src = (const int*)d_in[4];
    const int*   knn_dst = (const int*)d_in[5];
    const int*   knn_et  = (const int*)d_in[6];

    GGParams s1 { (const float*)d_in[8],  (const float*)d_in[9],  (const float*)d_in[10],
                  (const float*)d_in[11], (const float*)d_in[12], (const float*)d_in[13],
                  (const float*)d_in[14], (const float*)d_in[15], (const float*)d_in[16],
                  (const float*)d_in[17] };
    GGParams s2 { (const float*)d_in[18], (const float*)d_in[19], (const float*)d_in[20],
                  (const float*)d_in[21], (const float*)d_in[22], (const float*)d_in[23],
                  (const float*)d_in[24], (const float*)d_in[25], (const float*)d_in[26],
                  (const float*)d_in[27] };
    const float* w0 = (const float*)d_in[28];
    const float* b0 = (const float*)d_in[29];
    const float* w1 = (const float*)d_in[30];
    const float* b1 = (const float*)d_in[31];
    const float* wo = (const float*)d_in[32];
    const float* bo = (const float*)d_in[33];

    const int N = N_NODES;
    const size_t n128 = (size_t)N * 128;

    float* ws = (float*)d_ws;
    WsPtrs w;
    size_t off = 0;
    w.h      = ws + off;                       off += n128;
    w.ah     = (__hip_bfloat16*)(ws + off);    off += (size_t)N * 144;
    w.G      = ws + off;                       off += 4 * n128;
    w.hb     = (uint*)(w.G + 3 * n128);        // lives in G's spare quarter
    w.r1b    = (__hip_bfloat16*)(ws + off);    off += n128 / 2;
    w.featb  = (__hip_bfloat16*)(ws + off);    off += n128 / 4;
    w.bfragB = (__hip_bfloat16*)(ws + off);    off += 9 * 16384 / 2;
    w.gruB   = (__hip_bfloat16*)(ws + off);    off += 512 * 288 / 2;
    w.ro1B   = (__hip_bfloat16*)(ws + off);    off += 32768 / 2;
    w.ro2B   = (__hip_bfloat16*)(ws + off);    off += 16384 / 2;
    w.gruBias = ws + off;                      off += 512;
    w.ro1Bias = ws + off;                      off += 256;
    w.indptr  = (int*)(ws + off);              off += KN_TOT + 8;
    w.cursor  = (int*)(ws + off);              off += KN_TOT;
    w.partial = (int*)(ws + off);              off += 4096;
    w.elist   = (int*)(ws + off);              off += E_TOT;
    w.pooled  = ws + off;                      off += 64 * 128;
    w.x1      = ws + off;                      off += 64 * 256;
    w.x2      = ws + off;                      off += 64 * 128;

    // ---- merged CSR build ----
    hipMemsetAsync(w.cursor, 0, KN_TOT * sizeof(int), stream);
    hist2_kernel<<<(E_TOT + 255) / 256, 256, 0, stream>>>(bi_dst, bi_et, knn_dst, knn_et, w.cursor);
    scan1_kernel<<<KN_TOT / 256, 256, 0, stream>>>(w.cursor, w.indptr, w.partial);
    scan2b_kernel<<<1, 256, 0, stream>>>(w.partial, KN_TOT / 256, w.indptr + KN_TOT, E_TOT);
    scan3c_kernel<<<KN_TOT / 256, 256, 0, stream>>>(w.indptr, w.partial, w.cursor);
    fill2_kernel<<<(E_TOT + 255) / 256, 256, 0, stream>>>(bi_src, bi_dst, bi_et,
                                                          knn_src, knn_dst, knn_et,
                                                          w.cursor, w.elist);

    f2b_kernel<<<(N * 64) / 256, 256, 0, stream>>>(feat, w.featb);

    // Stage 1: bond graph (5 etypes), Fin=64
    run_stage<5>(stream, feat, nullptr, 64, s1, w, w.indptr, nullptr, w.r1b);
    // Stage 2: knn graph (9 etypes), feat = stage-1 readout (bf16)
    float* rout2 = w.G + 2 * n128;
    run_stage<9>(stream, nullptr, w.r1b, 128, s2, w, w.indptr + KN_BI, rout2, nullptr);

    // Stage 3: ligand pooling + MLP
    pool_kernel<<<64, 128, 0, stream>>>(rout2, w.pooled);
    {
        dim3 g1(1, 4);
        gemm_kernel<<<g1, 256, 0, stream>>>(w.pooled, 128, w0, 256, b0, w.x1, 256, 128, 1);
        dim3 g2(1, 2);
        gemm_kernel<<<g2, 256, 0, stream>>>(w.x1, 256, w1, 128, b1, w.x2, 128, 256, 1);
    }
    out_kernel<<<64, 64, 0, stream>>>(w.x2, wo, bo, (float*)d_out);
}